// Round 1
// baseline (784.134 us; speedup 1.0000x reference)
//
#include <hip/hip_runtime.h>
#include <hip/hip_bf16.h>
#include <math.h>

// ---------------------------------------------------------------------------
// InfomaxEncoder: message-passing GNN, 4 layers, H=128, R=50.
// Factorized: XW = X@W1_x + b1 (per layer); per-edge h1 = XW[col] + rbf@W1_r;
// S[i] = sum_{e: row[e]=i} silu(h1_e)   (symmetric-graph swap: aggregate on
// sorted row, gather from col — exact);  gi = S@Wc + deg*(b2@W_ih) + b_ih
// with Wc = W2@W_ih precomputed (linearity of the GRU input in aggr).
// ---------------------------------------------------------------------------

#define HH 128
#define RR 50
#define LL 4

__global__ __launch_bounds__(256) void init_x_kernel(
    const int* __restrict__ an, const float* __restrict__ emb,
    float* __restrict__ X, int count)
{
    int g = blockIdx.x * 256 + threadIdx.x;
    if (g >= count) return;
    int i = g >> 7, n = g & 127;
    int z = an[i];
    z = z < 0 ? 0 : (z > 99 ? 99 : z);
    X[g] = emb[z * HH + n];
}

__global__ __launch_bounds__(256) void zero_kernel(float* __restrict__ p, int count)
{
    int g = blockIdx.x * 256 + threadIdx.x;
    if (g < count) p[g] = 0.f;
}

__global__ __launch_bounds__(256) void dist_deg_kernel(
    const float* __restrict__ pos, const int* __restrict__ erow,
    const int* __restrict__ ecol, float* __restrict__ dist,
    float* __restrict__ DEG, int E)
{
    int e = blockIdx.x * 256 + threadIdx.x;
    if (e >= E) return;
    int r = erow[e], c = ecol[e];
    float dx = pos[r * 3 + 0] - pos[c * 3 + 0];
    float dy = pos[r * 3 + 1] - pos[c * 3 + 1];
    float dz = pos[r * 3 + 2] - pos[c * 3 + 2];
    dist[e] = sqrtf(dx * dx + dy * dy + dz * dz);
    atomicAdd(&DEG[r], 1.f);
}

// Wc[l][i][j] = sum_k W2[l][i][k] * W_ih[l][k][j];  grid 4*128 blocks x 384 thr
__global__ __launch_bounds__(384) void wc_kernel(
    const float* __restrict__ W2, const float* __restrict__ Wih,
    float* __restrict__ Wc)
{
    int l = blockIdx.x >> 7, i = blockIdx.x & 127, j = threadIdx.x;
    const float* w2row = W2 + ((size_t)l * HH + i) * HH;
    const float* wih = Wih + (size_t)l * HH * 384;
    float acc = 0.f;
#pragma unroll 4
    for (int k = 0; k < HH; ++k)
        acc = fmaf(w2row[k], wih[(size_t)k * 384 + j], acc);
    Wc[((size_t)l * HH + i) * 384 + j] = acc;
}

// P[l][j] = sum_k b2[l][k] * W_ih[l][k][j]
__global__ __launch_bounds__(384) void p_kernel(
    const float* __restrict__ b2, const float* __restrict__ Wih,
    float* __restrict__ P)
{
    int l = blockIdx.x, j = threadIdx.x;
    const float* b2l = b2 + (size_t)l * HH;
    const float* wih = Wih + (size_t)l * HH * 384;
    float acc = 0.f;
#pragma unroll 4
    for (int k = 0; k < HH; ++k)
        acc = fmaf(b2l[k], wih[(size_t)k * 384 + j], acc);
    P[l * 384 + j] = acc;
}

// XW = X @ W1_x + b1 : [N,128]@[128,128]
#define XAB 32
__global__ __launch_bounds__(256) void xw_kernel(
    const float* __restrict__ X, const float* __restrict__ W,
    const float* __restrict__ bias, float* __restrict__ XW, int N)
{
    __shared__ __align__(16) float A[XAB][HH];
    int tid = threadIdx.x;
    int abase = blockIdx.x * XAB;
    for (int idx = tid; idx < XAB * HH; idx += 256) {
        int a = idx >> 7, k = idx & 127;
        A[a][k] = (abase + a < N) ? X[(size_t)(abase + a) * HH + k] : 0.f;
    }
    __syncthreads();
    int n = tid & 127, s = tid >> 7;
    float acc[16];
#pragma unroll
    for (int i = 0; i < 16; ++i) acc[i] = 0.f;
    for (int kc = 0; kc < 32; ++kc) {
        float w0 = W[(4 * kc + 0) * HH + n];
        float w1 = W[(4 * kc + 1) * HH + n];
        float w2 = W[(4 * kc + 2) * HH + n];
        float w3 = W[(4 * kc + 3) * HH + n];
#pragma unroll
        for (int i = 0; i < 16; ++i) {
            float4 av = *(const float4*)&A[s * 16 + i][4 * kc];
            acc[i] = fmaf(av.x, w0, acc[i]);
            acc[i] = fmaf(av.y, w1, acc[i]);
            acc[i] = fmaf(av.z, w2, acc[i]);
            acc[i] = fmaf(av.w, w3, acc[i]);
        }
    }
    float b = bias[n];
#pragma unroll
    for (int i = 0; i < 16; ++i) {
        int a = abase + s * 16 + i;
        if (a < N) XW[(size_t)a * HH + n] = acc[i] + b;
    }
}

// Edge pass: S[row[e]] += silu(XW[col[e]] + rbf(d_e) @ W1_r)
#define TE 64
__global__ __launch_bounds__(256) void edge_pass_kernel(
    const float* __restrict__ XW, const float* __restrict__ W1r,
    const float* __restrict__ dist, const int* __restrict__ erow,
    const int* __restrict__ ecol, float* __restrict__ S, int E)
{
    __shared__ __align__(16) float rbf_lds[TE][52];   // stride 52*4=208B, 16B-aligned
    __shared__ float d_lds[TE];
    __shared__ int row_lds[TE];
    __shared__ int col_lds[TE];
    int tid = threadIdx.x;
    int base = blockIdx.x * TE;

    if (tid < TE) {
        int e = base + tid;
        if (e < E) {
            d_lds[tid] = dist[e];
            row_lds[tid] = erow[e];
            col_lds[tid] = ecol[e];
        } else {
            d_lds[tid] = 100.f;   // rbf -> 0
            row_lds[tid] = -1;
            col_lds[tid] = 0;
        }
    }
    __syncthreads();

    // rbf: centers = linspace(0,5,50) -> step 5/49; width = 0.1 -> 1/(2w^2)=50
    {
        int e = tid & 63, k0 = tid >> 6;
        float de = d_lds[e];
#pragma unroll
        for (int it = 0; it < 13; ++it) {
            int k = k0 + (it << 2);
            if (k < RR) {
                float c = (float)k * (5.0f / 49.0f);
                float t = de - c;
                rbf_lds[e][k] = __expf(-t * t * 50.0f);
            }
        }
    }
    __syncthreads();

    int n = tid & 127, s = tid >> 7;
    // W1_r column n resident in registers (50 VGPRs)
    float w[RR];
#pragma unroll
    for (int k = 0; k < RR; ++k) w[k] = W1r[k * HH + n];

    float acc = 0.f;
    int prev = -1;
    for (int t = 0; t < 32; ++t) {
        int el = (s << 5) + t;
        int dest = row_lds[el];
        if (dest < 0) break;            // only tail of last tile
        int src = col_lds[el];
        float h = XW[(size_t)src * HH + n];
        const float4* r4 = (const float4*)&rbf_lds[el][0];
#pragma unroll
        for (int kk = 0; kk < 12; ++kk) {
            float4 rv = r4[kk];
            h = fmaf(rv.x, w[4 * kk + 0], h);
            h = fmaf(rv.y, w[4 * kk + 1], h);
            h = fmaf(rv.z, w[4 * kk + 2], h);
            h = fmaf(rv.w, w[4 * kk + 3], h);
        }
        h = fmaf(rbf_lds[el][48], w[48], h);
        h = fmaf(rbf_lds[el][49], w[49], h);
        float sg = 1.0f / (1.0f + __expf(-h));
        float val = h * sg;             // silu
        if (dest != prev) {
            if (prev >= 0) atomicAdd(&S[(size_t)prev * HH + n], acc);
            prev = dest;
            acc = 0.f;
        }
        acc += val;
    }
    if (prev >= 0) atomicAdd(&S[(size_t)prev * HH + n], acc);
}

// GRU fused: gi = S@Wc + deg*P + b_ih ; gates ; X += (1-z)*n
#define GAB 16
__global__ __launch_bounds__(256) void gru_kernel(
    const float* __restrict__ S, const float* __restrict__ Wc,
    const float* __restrict__ P, const float* __restrict__ bih,
    const float* __restrict__ bhh, const float* __restrict__ DEG,
    float* __restrict__ X, int N)
{
    __shared__ __align__(16) float A[GAB][HH];
    int tid = threadIdx.x;
    int abase = blockIdx.x * GAB;
    for (int idx = tid; idx < GAB * HH; idx += 256) {
        int a = idx >> 7, k = idx & 127;
        A[a][k] = (abase + a < N) ? S[(size_t)(abase + a) * HH + k] : 0.f;
    }
    __syncthreads();
    int n = tid & 127, s = tid >> 7;
    float acc0[8], acc1[8], acc2[8];
#pragma unroll
    for (int i = 0; i < 8; ++i) { acc0[i] = 0.f; acc1[i] = 0.f; acc2[i] = 0.f; }
    for (int kc = 0; kc < 32; ++kc) {
        float wr[4], wz[4], wn[4];
#pragma unroll
        for (int q = 0; q < 4; ++q) {
            int k = 4 * kc + q;
            wr[q] = Wc[(size_t)k * 384 + n];
            wz[q] = Wc[(size_t)k * 384 + 128 + n];
            wn[q] = Wc[(size_t)k * 384 + 256 + n];
        }
#pragma unroll
        for (int i = 0; i < 8; ++i) {
            float4 av = *(const float4*)&A[s * 8 + i][4 * kc];
            acc0[i] = fmaf(av.x, wr[0], fmaf(av.y, wr[1], fmaf(av.z, wr[2], fmaf(av.w, wr[3], acc0[i]))));
            acc1[i] = fmaf(av.x, wz[0], fmaf(av.y, wz[1], fmaf(av.z, wz[2], fmaf(av.w, wz[3], acc1[i]))));
            acc2[i] = fmaf(av.x, wn[0], fmaf(av.y, wn[1], fmaf(av.z, wn[2], fmaf(av.w, wn[3], acc2[i]))));
        }
    }
    float pr = P[n], pz = P[128 + n], pn = P[256 + n];
    float br = bih[n], bz = bih[128 + n], bn = bih[256 + n];
    float hr = bhh[n], hz = bhh[128 + n], hn = bhh[256 + n];
#pragma unroll
    for (int i = 0; i < 8; ++i) {
        int a = abase + s * 8 + i;
        if (a >= N) continue;
        float deg = DEG[a];
        float g0 = acc0[i] + deg * pr + br;
        float g1 = acc1[i] + deg * pz + bz;
        float g2 = acc2[i] + deg * pn + bn;
        float r = 1.f / (1.f + __expf(-(g0 + hr)));
        float z = 1.f / (1.f + __expf(-(g1 + hz)));
        float nn = tanhf(g2 + r * hn);
        X[(size_t)a * HH + n] += (1.f - z) * nn;
    }
}

// LayerNorm -> d_out x region; atomic pooled sums
__global__ __launch_bounds__(256) void ln_kernel(
    const float* __restrict__ X, const float* __restrict__ g,
    const float* __restrict__ b, const int* __restrict__ batch,
    float* __restrict__ out, float* __restrict__ gsum,
    float* __restrict__ gcnt, int N)
{
    int a = blockIdx.x * 4 + (threadIdx.x >> 6);
    int lane = threadIdx.x & 63;
    if (a >= N) return;
    float v0 = X[(size_t)a * HH + lane];
    float v1 = X[(size_t)a * HH + 64 + lane];
    float sm = v0 + v1;
    for (int off = 32; off > 0; off >>= 1) sm += __shfl_xor(sm, off, 64);
    float mu = sm * (1.f / 128.f);
    float d0 = v0 - mu, d1 = v1 - mu;
    float vq = d0 * d0 + d1 * d1;
    for (int off = 32; off > 0; off >>= 1) vq += __shfl_xor(vq, off, 64);
    float inv = rsqrtf(vq * (1.f / 128.f) + 1e-5f);
    float y0 = d0 * inv * g[lane] + b[lane];
    float y1 = d1 * inv * g[64 + lane] + b[64 + lane];
    out[(size_t)a * HH + lane] = y0;
    out[(size_t)a * HH + 64 + lane] = y1;
    int bt = batch[a];
    atomicAdd(&gsum[(size_t)bt * HH + lane], y0);
    atomicAdd(&gsum[(size_t)bt * HH + 64 + lane], y1);
    if (lane == 0) atomicAdd(&gcnt[bt], 1.f);
}

__global__ __launch_bounds__(256) void pool_kernel(
    const float* __restrict__ gsum, const float* __restrict__ gcnt,
    float* __restrict__ out, int count)
{
    int gidx = blockIdx.x * 256 + threadIdx.x;
    if (gidx >= count) return;
    int m = gidx >> 7;
    out[gidx] = gsum[gidx] / fmaxf(gcnt[m], 1.f);
}

extern "C" void kernel_launch(void* const* d_in, const int* in_sizes, int n_in,
                              void* d_out, int out_size, void* d_ws, size_t ws_size,
                              hipStream_t stream)
{
    const int*   an   = (const int*)d_in[0];
    const float* pos  = (const float*)d_in[1];
    const int*   bat  = (const int*)d_in[2];
    const int*   eidx = (const int*)d_in[3];
    const float* emb  = (const float*)d_in[4];
    const float* W1   = (const float*)d_in[5];
    const float* b1   = (const float*)d_in[6];
    const float* W2   = (const float*)d_in[7];
    const float* b2   = (const float*)d_in[8];
    const float* Wih  = (const float*)d_in[9];
    const float* bih  = (const float*)d_in[10];
    const float* bhh  = (const float*)d_in[11];
    const float* lng  = (const float*)d_in[12];
    const float* lnb  = (const float*)d_in[13];

    int N = in_sizes[0];
    int E = in_sizes[3] / 2;
    int M = out_size / HH - N;
    const int* erow = eidx;
    const int* ecol = eidx + E;

    float* ws   = (float*)d_ws;
    float* X    = ws;
    float* S    = X + (size_t)N * HH;
    float* XW   = S + (size_t)N * HH;
    float* dist = XW + (size_t)N * HH;
    float* DEG  = dist + E;
    float* Wc   = DEG + N;
    float* P    = Wc + (size_t)LL * HH * 384;
    float* gsum = P + LL * 384;
    float* gcnt = gsum + (size_t)M * HH;

    float* outx = (float*)d_out;
    float* outg = outx + (size_t)N * HH;

    init_x_kernel<<<(N * HH + 255) / 256, 256, 0, stream>>>(an, emb, X, N * HH);
    zero_kernel<<<(N + 255) / 256, 256, 0, stream>>>(DEG, N);
    zero_kernel<<<(M * HH + M + 255) / 256, 256, 0, stream>>>(gsum, M * HH + M);
    dist_deg_kernel<<<(E + 255) / 256, 256, 0, stream>>>(pos, erow, ecol, dist, DEG, E);
    wc_kernel<<<LL * HH, 384, 0, stream>>>(W2, Wih, Wc);
    p_kernel<<<LL, 384, 0, stream>>>(b2, Wih, P);

    for (int l = 0; l < LL; ++l) {
        const float* W1l = W1 + (size_t)l * 178 * HH;
        xw_kernel<<<(N + XAB - 1) / XAB, 256, 0, stream>>>(X, W1l, b1 + l * HH, XW, N);
        zero_kernel<<<(N * HH + 255) / 256, 256, 0, stream>>>(S, N * HH);
        edge_pass_kernel<<<(E + TE - 1) / TE, 256, 0, stream>>>(
            XW, W1l + HH * HH, dist, erow, ecol, S, E);
        gru_kernel<<<(N + GAB - 1) / GAB, 256, 0, stream>>>(
            S, Wc + (size_t)l * HH * 384, P + l * 384,
            bih + l * 384, bhh + l * 384, DEG, X, N);
    }

    ln_kernel<<<(N + 3) / 4, 256, 0, stream>>>(X, lng, lnb, bat, outx, gsum, gcnt, N);
    pool_kernel<<<(M * HH + 255) / 256, 256, 0, stream>>>(gsum, gcnt, outg, M * HH);
}

// Round 2
// 640.450 us; speedup vs baseline: 1.2243x; 1.2243x over previous
//
#include <hip/hip_runtime.h>
#include <hip/hip_bf16.h>
#include <math.h>

// ---------------------------------------------------------------------------
// InfomaxEncoder, round 2: edge pass via bf16 MFMA.
//   XW = X@W1_x + b1 (fp32)
//   per 16-edge tile: C^T = W1rT(bf16) x rbf^T(bf16) via mfma_f32_16x16x32_bf16
//     -> lane owns ONE edge (col=lane&15) x 32 n-values (8 ntiles x 4 regs)
//   silu(C + XW[col]) accumulated in registers over the atom's sorted edge run
//   (rowptr), reduced across the 16 edge-classes with an index-splitting
//   butterfly (30 shuffles), stored directly to S (no atomics, no zeroing).
//   GRU: gi = S@Wc + deg*P + b_ih with Wc=W2@W_ih precomputed (exact).
// ---------------------------------------------------------------------------

#define HH 128
#define RR 50
#define LL 4

typedef __attribute__((ext_vector_type(8))) short short8;
typedef __attribute__((ext_vector_type(4))) float floatx4;

__device__ __forceinline__ unsigned short f2bf(float f) {
    unsigned u = __float_as_uint(f);
    unsigned r = (u + 0x7fffu + ((u >> 16) & 1u)) >> 16;
    return (unsigned short)r;
}

__global__ __launch_bounds__(256) void init_x_kernel(
    const int* __restrict__ an, const float* __restrict__ emb,
    float* __restrict__ X, int count)
{
    int g = blockIdx.x * 256 + threadIdx.x;
    if (g >= count) return;
    int i = g >> 7, n = g & 127;
    int z = an[i];
    z = z < 0 ? 0 : (z > 99 ? 99 : z);
    X[g] = emb[z * HH + n];
}

__global__ __launch_bounds__(256) void zero_kernel(float* __restrict__ p, int count)
{
    int g = blockIdx.x * 256 + threadIdx.x;
    if (g < count) p[g] = 0.f;
}

// rowptr from sorted erow: rowptr[r] = first e with erow[e] >= r; rowptr[N]=E
__global__ __launch_bounds__(256) void rowptr_kernel(
    const int* __restrict__ erow, int* __restrict__ rowptr, int E, int N)
{
    int e = blockIdx.x * 256 + threadIdx.x;
    if (e >= E) return;
    int rc = erow[e];
    int rp = (e > 0) ? erow[e - 1] : -1;
    for (int r = rp + 1; r <= rc; ++r) rowptr[r] = e;
    if (e == E - 1)
        for (int r = rc + 1; r <= N; ++r) rowptr[r] = E;
}

// RBF_bf16[Eall][64]: k<50 -> exp(-50*(d-k*5/49)^2), else 0; pad rows zero.
__global__ __launch_bounds__(256) void rbf_kernel(
    const float* __restrict__ pos, const int* __restrict__ erow,
    const int* __restrict__ ecol, unsigned short* __restrict__ RBF,
    int E, int Eall)
{
    int e = blockIdx.x * 256 + threadIdx.x;
    if (e >= Eall) return;
    unsigned int* dst = (unsigned int*)(RBF + (size_t)e * 64);
    if (e >= E) {
#pragma unroll
        for (int i = 0; i < 32; ++i) dst[i] = 0u;
        return;
    }
    int r = erow[e], c = ecol[e];
    float dx = pos[r * 3 + 0] - pos[c * 3 + 0];
    float dy = pos[r * 3 + 1] - pos[c * 3 + 1];
    float dz = pos[r * 3 + 2] - pos[c * 3 + 2];
    float d = sqrtf(dx * dx + dy * dy + dz * dz);
#pragma unroll
    for (int i = 0; i < 32; ++i) {
        int k0 = 2 * i, k1 = 2 * i + 1;
        float v0 = 0.f, v1 = 0.f;
        if (k0 < RR) { float t = d - (float)k0 * (5.0f / 49.0f); v0 = __expf(-t * t * 50.0f); }
        if (k1 < RR) { float t = d - (float)k1 * (5.0f / 49.0f); v1 = __expf(-t * t * 50.0f); }
        dst[i] = (unsigned)f2bf(v0) | ((unsigned)f2bf(v1) << 16);
    }
}

// W1rT_bf16[L][128n][64k]: = bf16(W1[l][128+k][n]) for k<50 else 0
__global__ __launch_bounds__(256) void w1rt_kernel(
    const float* __restrict__ W1, unsigned short* __restrict__ W1rT)
{
    int idx = blockIdx.x * 256 + threadIdx.x;
    if (idx >= LL * HH * 64) return;
    int l = idx >> 13, rem = idx & 8191, n = rem >> 6, k = rem & 63;
    float v = (k < RR) ? W1[((size_t)l * 178 + 128 + k) * HH + n] : 0.f;
    W1rT[idx] = f2bf(v);
}

// Wc[l][i][j] = sum_k W2[l][i][k] * W_ih[l][k][j]
__global__ __launch_bounds__(384) void wc_kernel(
    const float* __restrict__ W2, const float* __restrict__ Wih,
    float* __restrict__ Wc)
{
    int l = blockIdx.x >> 7, i = blockIdx.x & 127, j = threadIdx.x;
    const float* w2row = W2 + ((size_t)l * HH + i) * HH;
    const float* wih = Wih + (size_t)l * HH * 384;
    float acc = 0.f;
#pragma unroll 4
    for (int k = 0; k < HH; ++k)
        acc = fmaf(w2row[k], wih[(size_t)k * 384 + j], acc);
    Wc[((size_t)l * HH + i) * 384 + j] = acc;
}

// P[l][j] = sum_k b2[l][k] * W_ih[l][k][j]
__global__ __launch_bounds__(384) void p_kernel(
    const float* __restrict__ b2, const float* __restrict__ Wih,
    float* __restrict__ P)
{
    int l = blockIdx.x, j = threadIdx.x;
    const float* b2l = b2 + (size_t)l * HH;
    const float* wih = Wih + (size_t)l * HH * 384;
    float acc = 0.f;
#pragma unroll 4
    for (int k = 0; k < HH; ++k)
        acc = fmaf(b2l[k], wih[(size_t)k * 384 + j], acc);
    P[l * 384 + j] = acc;
}

// XW = X @ W1_x + b1 : [N,128]@[128,128]
#define XAB 32
__global__ __launch_bounds__(256) void xw_kernel(
    const float* __restrict__ X, const float* __restrict__ W,
    const float* __restrict__ bias, float* __restrict__ XW, int N)
{
    __shared__ __align__(16) float A[XAB][HH];
    int tid = threadIdx.x;
    int abase = blockIdx.x * XAB;
    for (int idx = tid; idx < XAB * HH; idx += 256) {
        int a = idx >> 7, k = idx & 127;
        A[a][k] = (abase + a < N) ? X[(size_t)(abase + a) * HH + k] : 0.f;
    }
    __syncthreads();
    int n = tid & 127, s = tid >> 7;
    float acc[16];
#pragma unroll
    for (int i = 0; i < 16; ++i) acc[i] = 0.f;
    for (int kc = 0; kc < 32; ++kc) {
        float w0 = W[(4 * kc + 0) * HH + n];
        float w1 = W[(4 * kc + 1) * HH + n];
        float w2 = W[(4 * kc + 2) * HH + n];
        float w3 = W[(4 * kc + 3) * HH + n];
#pragma unroll
        for (int i = 0; i < 16; ++i) {
            float4 av = *(const float4*)&A[s * 16 + i][4 * kc];
            acc[i] = fmaf(av.x, w0, acc[i]);
            acc[i] = fmaf(av.y, w1, acc[i]);
            acc[i] = fmaf(av.z, w2, acc[i]);
            acc[i] = fmaf(av.w, w3, acc[i]);
        }
    }
    float b = bias[n];
#pragma unroll
    for (int i = 0; i < 16; ++i) {
        int a = abase + s * 16 + i;
        if (a < N) XW[(size_t)a * HH + n] = acc[i] + b;
    }
}

// ---------------------------------------------------------------------------
// Edge pass: one wave owns APW atoms; per 16-edge tile:
//   D[n_local][edge] = W1rT_tile(A) x RBF_tile(B) via 2 chained MFMAs x 8 ntile
//   lane: edge = ebase + (lane&15); n = ntile*16 + (lane>>4)*4 + reg
// ---------------------------------------------------------------------------
#define APW 2
__global__ __launch_bounds__(256) void edge_mfma_kernel(
    const float* __restrict__ XW, const unsigned short* __restrict__ W1rT,
    const unsigned short* __restrict__ RBF, const int* __restrict__ rowptr,
    const int* __restrict__ ecol, float* __restrict__ S, int N)
{
    int wave = (blockIdx.x << 2) + (threadIdx.x >> 6);
    int lane = threadIdx.x & 63;
    int a0 = wave * APW;
    if (a0 >= N) return;
    int c = lane & 15, q = lane >> 4;

    // A-frags (layer weights), wave-constant: A[m=c][k=q*8+j]
    short8 Afr[8][2];
#pragma unroll
    for (int nt = 0; nt < 8; ++nt) {
        Afr[nt][0] = *(const short8*)&W1rT[(nt * 16 + c) * 64 + q * 8];
        Afr[nt][1] = *(const short8*)&W1rT[(nt * 16 + c) * 64 + 32 + q * 8];
    }

    int aend = a0 + APW; if (aend > N) aend = N;
    for (int a = a0; a < aend; ++a) {
        int es = rowptr[a], ee = rowptr[a + 1];
        float acc[8][4];
#pragma unroll
        for (int nt = 0; nt < 8; ++nt)
#pragma unroll
            for (int r = 0; r < 4; ++r) acc[nt][r] = 0.f;

        for (int eb = es; eb < ee; eb += 16) {
            int e = eb + c;
            // B-frags: B[k=q*8+j][edge=c] = RBF[e][k]; pad rows are zero
            short8 B0 = *(const short8*)&RBF[(size_t)e * 64 + q * 8];
            short8 B1 = *(const short8*)&RBF[(size_t)e * 64 + 32 + q * 8];
            bool valid = e < ee;
            int col = ecol[valid ? e : ee - 1];
            const float* xwrow = XW + (size_t)col * HH;
#pragma unroll
            for (int nt = 0; nt < 8; ++nt) {
                floatx4 C = {0.f, 0.f, 0.f, 0.f};
                C = __builtin_amdgcn_mfma_f32_16x16x32_bf16(Afr[nt][0], B0, C, 0, 0, 0);
                C = __builtin_amdgcn_mfma_f32_16x16x32_bf16(Afr[nt][1], B1, C, 0, 0, 0);
                float4 g = *(const float4*)&xwrow[nt * 16 + q * 4];
                float gg[4] = {g.x, g.y, g.z, g.w};
#pragma unroll
                for (int r = 0; r < 4; ++r) {
                    float h = C[r] + gg[r];
                    float v = h / (1.f + __expf(-h));   // silu
                    acc[nt][r] += valid ? v : 0.f;
                }
            }
        }

        // Index-splitting butterfly over the 16 edge-classes (c bits).
        int b3 = (c >> 3) & 1, b0 = c & 1, b1 = (c >> 1) & 1, b2 = (c >> 2) & 1;
        // bit3: r 4->2 (keep r-pair b3)
        float s16[8][2];
#pragma unroll
        for (int t = 0; t < 8; ++t)
#pragma unroll
            for (int p = 0; p < 2; ++p) {
                float keep = b3 ? acc[t][2 + p] : acc[t][p];
                float send = b3 ? acc[t][p] : acc[t][2 + p];
                s16[t][p] = keep + __shfl_xor(send, 8, 64);
            }
        // bit0: nt 8->4 (keep nt with bit0 == b0) ; logical nt = 2t + b0
        float s8[4][2];
#pragma unroll
        for (int t = 0; t < 4; ++t)
#pragma unroll
            for (int p = 0; p < 2; ++p) {
                float keep = b0 ? s16[2 * t + 1][p] : s16[2 * t][p];
                float send = b0 ? s16[2 * t][p] : s16[2 * t + 1][p];
                s8[t][p] = keep + __shfl_xor(send, 1, 64);
            }
        // bit1: 4->2 ; logical nt = 4u + 2*b1 + b0
        float s4[2][2];
#pragma unroll
        for (int u = 0; u < 2; ++u)
#pragma unroll
            for (int p = 0; p < 2; ++p) {
                float keep = b1 ? s8[2 * u + 1][p] : s8[2 * u][p];
                float send = b1 ? s8[2 * u][p] : s8[2 * u + 1][p];
                s4[u][p] = keep + __shfl_xor(send, 2, 64);
            }
        // bit2: 2->1 ; final nt = 4*b2 + 2*b1 + b0 = c&7
        float s2[2];
#pragma unroll
        for (int p = 0; p < 2; ++p) {
            float keep = b2 ? s4[1][p] : s4[0][p];
            float send = b2 ? s4[0][p] : s4[1][p];
            s2[p] = keep + __shfl_xor(send, 4, 64);
        }
        // store: n = (c&7)*16 + q*4 + b3*2 + {0,1}
        float2 st; st.x = s2[0]; st.y = s2[1];
        *(float2*)&S[(size_t)a * HH + (c & 7) * 16 + (q << 2) + (b3 << 1)] = st;
    }
}

// GRU fused: gi = S@Wc + deg*P + b_ih ; gates ; X += (1-z)*n
#define GAB 16
__global__ __launch_bounds__(256) void gru_kernel(
    const float* __restrict__ S, const float* __restrict__ Wc,
    const float* __restrict__ P, const float* __restrict__ bih,
    const float* __restrict__ bhh, const int* __restrict__ rowptr,
    float* __restrict__ X, int N)
{
    __shared__ __align__(16) float A[GAB][HH];
    int tid = threadIdx.x;
    int abase = blockIdx.x * GAB;
    for (int idx = tid; idx < GAB * HH; idx += 256) {
        int a = idx >> 7, k = idx & 127;
        A[a][k] = (abase + a < N) ? S[(size_t)(abase + a) * HH + k] : 0.f;
    }
    __syncthreads();
    int n = tid & 127, s = tid >> 7;
    float acc0[8], acc1[8], acc2[8];
#pragma unroll
    for (int i = 0; i < 8; ++i) { acc0[i] = 0.f; acc1[i] = 0.f; acc2[i] = 0.f; }
    for (int kc = 0; kc < 32; ++kc) {
        float wr[4], wz[4], wn[4];
#pragma unroll
        for (int qq = 0; qq < 4; ++qq) {
            int k = 4 * kc + qq;
            wr[qq] = Wc[(size_t)k * 384 + n];
            wz[qq] = Wc[(size_t)k * 384 + 128 + n];
            wn[qq] = Wc[(size_t)k * 384 + 256 + n];
        }
#pragma unroll
        for (int i = 0; i < 8; ++i) {
            float4 av = *(const float4*)&A[s * 8 + i][4 * kc];
            acc0[i] = fmaf(av.x, wr[0], fmaf(av.y, wr[1], fmaf(av.z, wr[2], fmaf(av.w, wr[3], acc0[i]))));
            acc1[i] = fmaf(av.x, wz[0], fmaf(av.y, wz[1], fmaf(av.z, wz[2], fmaf(av.w, wz[3], acc1[i]))));
            acc2[i] = fmaf(av.x, wn[0], fmaf(av.y, wn[1], fmaf(av.z, wn[2], fmaf(av.w, wn[3], acc2[i]))));
        }
    }
    float pr = P[n], pz = P[128 + n], pn = P[256 + n];
    float br = bih[n], bz = bih[128 + n], bn = bih[256 + n];
    float hr = bhh[n], hz = bhh[128 + n], hn = bhh[256 + n];
#pragma unroll
    for (int i = 0; i < 8; ++i) {
        int a = abase + s * 8 + i;
        if (a >= N) continue;
        float deg = (float)(rowptr[a + 1] - rowptr[a]);
        float g0 = acc0[i] + deg * pr + br;
        float g1 = acc1[i] + deg * pz + bz;
        float g2 = acc2[i] + deg * pn + bn;
        float r = 1.f / (1.f + __expf(-(g0 + hr)));
        float z = 1.f / (1.f + __expf(-(g1 + hz)));
        float nn = tanhf(g2 + r * hn);
        X[(size_t)a * HH + n] += (1.f - z) * nn;
    }
}

// LayerNorm -> d_out x region; atomic pooled sums
__global__ __launch_bounds__(256) void ln_kernel(
    const float* __restrict__ X, const float* __restrict__ g,
    const float* __restrict__ b, const int* __restrict__ batch,
    float* __restrict__ out, float* __restrict__ gsum,
    float* __restrict__ gcnt, int N)
{
    int a = blockIdx.x * 4 + (threadIdx.x >> 6);
    int lane = threadIdx.x & 63;
    if (a >= N) return;
    float v0 = X[(size_t)a * HH + lane];
    float v1 = X[(size_t)a * HH + 64 + lane];
    float sm = v0 + v1;
    for (int off = 32; off > 0; off >>= 1) sm += __shfl_xor(sm, off, 64);
    float mu = sm * (1.f / 128.f);
    float d0 = v0 - mu, d1 = v1 - mu;
    float vq = d0 * d0 + d1 * d1;
    for (int off = 32; off > 0; off >>= 1) vq += __shfl_xor(vq, off, 64);
    float inv = rsqrtf(vq * (1.f / 128.f) + 1e-5f);
    float y0 = d0 * inv * g[lane] + b[lane];
    float y1 = d1 * inv * g[64 + lane] + b[64 + lane];
    out[(size_t)a * HH + lane] = y0;
    out[(size_t)a * HH + 64 + lane] = y1;
    int bt = batch[a];
    atomicAdd(&gsum[(size_t)bt * HH + lane], y0);
    atomicAdd(&gsum[(size_t)bt * HH + 64 + lane], y1);
    if (lane == 0) atomicAdd(&gcnt[bt], 1.f);
}

__global__ __launch_bounds__(256) void pool_kernel(
    const float* __restrict__ gsum, const float* __restrict__ gcnt,
    float* __restrict__ out, int count)
{
    int gidx = blockIdx.x * 256 + threadIdx.x;
    if (gidx >= count) return;
    int m = gidx >> 7;
    out[gidx] = gsum[gidx] / fmaxf(gcnt[m], 1.f);
}

extern "C" void kernel_launch(void* const* d_in, const int* in_sizes, int n_in,
                              void* d_out, int out_size, void* d_ws, size_t ws_size,
                              hipStream_t stream)
{
    const int*   an   = (const int*)d_in[0];
    const float* pos  = (const float*)d_in[1];
    const int*   bat  = (const int*)d_in[2];
    const int*   eidx = (const int*)d_in[3];
    const float* emb  = (const float*)d_in[4];
    const float* W1   = (const float*)d_in[5];
    const float* b1   = (const float*)d_in[6];
    const float* W2   = (const float*)d_in[7];
    const float* b2   = (const float*)d_in[8];
    const float* Wih  = (const float*)d_in[9];
    const float* bih  = (const float*)d_in[10];
    const float* bhh  = (const float*)d_in[11];
    const float* lng  = (const float*)d_in[12];
    const float* lnb  = (const float*)d_in[13];

    int N = in_sizes[0];
    int E = in_sizes[3] / 2;
    int M = out_size / HH - N;
    int Eall = ((E + 15) & ~15) + 16;
    const int* erow = eidx;
    const int* ecol = eidx + E;

    float* ws   = (float*)d_ws;
    size_t off = 0;
    float* X    = ws + off; off += (size_t)N * HH;
    float* S    = ws + off; off += (size_t)N * HH;
    float* XW   = ws + off; off += (size_t)N * HH;
    float* Wc   = ws + off; off += (size_t)LL * HH * 384;
    float* P    = ws + off; off += LL * 384;
    float* gsum = ws + off; off += (size_t)M * HH;
    float* gcnt = ws + off; off += M;
    int* rowptr = (int*)(ws + off); off += N + 1;
    off = (off + 3) & ~(size_t)3;
    unsigned short* RBF  = (unsigned short*)(ws + off); off += (size_t)Eall * 32;
    unsigned short* W1rT = (unsigned short*)(ws + off); off += (size_t)LL * HH * 32;

    float* outx = (float*)d_out;
    float* outg = outx + (size_t)N * HH;

    // one-time prep
    init_x_kernel<<<(N * HH + 255) / 256, 256, 0, stream>>>(an, emb, X, N * HH);
    zero_kernel<<<(M * HH + M + 255) / 256, 256, 0, stream>>>(gsum, M * HH + M);
    rowptr_kernel<<<(E + 255) / 256, 256, 0, stream>>>(erow, rowptr, E, N);
    rbf_kernel<<<(Eall + 255) / 256, 256, 0, stream>>>(pos, erow, ecol, RBF, E, Eall);
    w1rt_kernel<<<(LL * HH * 64 + 255) / 256, 256, 0, stream>>>(W1, W1rT);
    wc_kernel<<<LL * HH, 384, 0, stream>>>(W2, Wih, Wc);
    p_kernel<<<LL, 384, 0, stream>>>(b2, Wih, P);

    int edge_waves = (N + APW - 1) / APW;
    int edge_blocks = (edge_waves + 3) / 4;

    for (int l = 0; l < LL; ++l) {
        const float* W1l = W1 + (size_t)l * 178 * HH;
        xw_kernel<<<(N + XAB - 1) / XAB, 256, 0, stream>>>(X, W1l, b1 + l * HH, XW, N);
        edge_mfma_kernel<<<edge_blocks, 256, 0, stream>>>(
            XW, W1rT + (size_t)l * HH * 64, RBF, rowptr, ecol, S, N);
        gru_kernel<<<(N + GAB - 1) / GAB, 256, 0, stream>>>(
            S, Wc + (size_t)l * HH * 384, P + l * 384,
            bih + l * 384, bhh + l * 384, rowptr, X, N);
    }

    ln_kernel<<<(N + 3) / 4, 256, 0, stream>>>(X, lng, lnb, bat, outx, gsum, gcnt, N);
    pool_kernel<<<(M * HH + 255) / 256, 256, 0, stream>>>(gsum, gcnt, outg, M * HH);
}

// Round 3
// 501.461 us; speedup vs baseline: 1.5637x; 1.2772x over previous
//
#include <hip/hip_runtime.h>
#include <hip/hip_bf16.h>
#include <math.h>

// ---------------------------------------------------------------------------
// InfomaxEncoder, round 3:
//  - ln/pool: NO atomics (batch is sorted -> bptr segments, block-per-molecule)
//  - edge: APW=1, prefetch next tile (B-frags + ecol), rcp-intrinsic silu
//  - gru(l) fused with xw(l+1) (X tile staged through LDS)
// Factorizations (exact): XW = X@W1_x + b1; S = segsum silu(XW[col] + rbf@W1r)
// over sorted rows; gi = S@Wc + deg*P + b_ih, Wc = W2@W_ih, P = b2@W_ih.
// ---------------------------------------------------------------------------

#define HH 128
#define RR 50
#define LL 4

typedef __attribute__((ext_vector_type(8))) short short8;
typedef __attribute__((ext_vector_type(4))) float floatx4;

__device__ __forceinline__ unsigned short f2bf(float f) {
    unsigned u = __float_as_uint(f);
    unsigned r = (u + 0x7fffu + ((u >> 16) & 1u)) >> 16;
    return (unsigned short)r;
}
__device__ __forceinline__ float fast_sigmoid(float x) {
    return __builtin_amdgcn_rcpf(1.f + __expf(-x));
}
__device__ __forceinline__ float fast_tanh(float x) {
    x = fminf(fmaxf(x, -15.f), 15.f);
    float t = __expf(2.f * x);
    return (t - 1.f) * __builtin_amdgcn_rcpf(t + 1.f);
}

__global__ __launch_bounds__(256) void init_x_kernel(
    const int* __restrict__ an, const float* __restrict__ emb,
    float* __restrict__ X, int count)
{
    int g = blockIdx.x * 256 + threadIdx.x;
    if (g >= count) return;
    int i = g >> 7, n = g & 127;
    int z = an[i];
    z = z < 0 ? 0 : (z > 99 ? 99 : z);
    X[g] = emb[z * HH + n];
}

// rowptr from sorted erow; bptr from sorted batch (both in one kernel)
__global__ __launch_bounds__(256) void ptr_kernel(
    const int* __restrict__ erow, int* __restrict__ rowptr, int E, int N,
    const int* __restrict__ batch, int* __restrict__ bptr, int M)
{
    int i = blockIdx.x * 256 + threadIdx.x;
    if (i < E) {
        int rc = erow[i];
        int rp = (i > 0) ? erow[i - 1] : -1;
        for (int r = rp + 1; r <= rc; ++r) rowptr[r] = i;
        if (i == E - 1)
            for (int r = rc + 1; r <= N; ++r) rowptr[r] = E;
    }
    if (i < N) {
        int bc = batch[i];
        int bp = (i > 0) ? batch[i - 1] : -1;
        for (int m = bp + 1; m <= bc; ++m) bptr[m] = i;
        if (i == N - 1)
            for (int m = bc + 1; m <= M; ++m) bptr[m] = N;
    }
}

// RBF_bf16[Eall][64]: k<50 -> exp(-50*(d-k*5/49)^2), else 0; pad rows zero.
__global__ __launch_bounds__(256) void rbf_kernel(
    const float* __restrict__ pos, const int* __restrict__ erow,
    const int* __restrict__ ecol, unsigned short* __restrict__ RBF,
    int E, int Eall)
{
    int e = blockIdx.x * 256 + threadIdx.x;
    if (e >= Eall) return;
    unsigned int* dst = (unsigned int*)(RBF + (size_t)e * 64);
    if (e >= E) {
#pragma unroll
        for (int i = 0; i < 32; ++i) dst[i] = 0u;
        return;
    }
    int r = erow[e], c = ecol[e];
    float dx = pos[r * 3 + 0] - pos[c * 3 + 0];
    float dy = pos[r * 3 + 1] - pos[c * 3 + 1];
    float dz = pos[r * 3 + 2] - pos[c * 3 + 2];
    float d = sqrtf(dx * dx + dy * dy + dz * dz);
#pragma unroll
    for (int i = 0; i < 32; ++i) {
        int k0 = 2 * i, k1 = 2 * i + 1;
        float v0 = 0.f, v1 = 0.f;
        if (k0 < RR) { float t = d - (float)k0 * (5.0f / 49.0f); v0 = __expf(-t * t * 50.0f); }
        if (k1 < RR) { float t = d - (float)k1 * (5.0f / 49.0f); v1 = __expf(-t * t * 50.0f); }
        dst[i] = (unsigned)f2bf(v0) | ((unsigned)f2bf(v1) << 16);
    }
}

// W1rT_bf16[L][128n][64k]
__global__ __launch_bounds__(256) void w1rt_kernel(
    const float* __restrict__ W1, unsigned short* __restrict__ W1rT)
{
    int idx = blockIdx.x * 256 + threadIdx.x;
    if (idx >= LL * HH * 64) return;
    int l = idx >> 13, rem = idx & 8191, n = rem >> 6, k = rem & 63;
    float v = (k < RR) ? W1[((size_t)l * 178 + 128 + k) * HH + n] : 0.f;
    W1rT[idx] = f2bf(v);
}

// Wc[l][i][j] = sum_k W2[l][i][k] * W_ih[l][k][j]
__global__ __launch_bounds__(384) void wc_kernel(
    const float* __restrict__ W2, const float* __restrict__ Wih,
    float* __restrict__ Wc)
{
    int l = blockIdx.x >> 7, i = blockIdx.x & 127, j = threadIdx.x;
    const float* w2row = W2 + ((size_t)l * HH + i) * HH;
    const float* wih = Wih + (size_t)l * HH * 384;
    float acc = 0.f;
#pragma unroll 4
    for (int k = 0; k < HH; ++k)
        acc = fmaf(w2row[k], wih[(size_t)k * 384 + j], acc);
    Wc[((size_t)l * HH + i) * 384 + j] = acc;
}

// P[l][j] = sum_k b2[l][k] * W_ih[l][k][j]
__global__ __launch_bounds__(384) void p_kernel(
    const float* __restrict__ b2, const float* __restrict__ Wih,
    float* __restrict__ P)
{
    int l = blockIdx.x, j = threadIdx.x;
    const float* b2l = b2 + (size_t)l * HH;
    const float* wih = Wih + (size_t)l * HH * 384;
    float acc = 0.f;
#pragma unroll 4
    for (int k = 0; k < HH; ++k)
        acc = fmaf(b2l[k], wih[(size_t)k * 384 + j], acc);
    P[l * 384 + j] = acc;
}

// XW = X @ W1_x + b1 (layer 0 only; later layers fused into grux)
#define XAB 32
__global__ __launch_bounds__(256) void xw_kernel(
    const float* __restrict__ X, const float* __restrict__ W,
    const float* __restrict__ bias, float* __restrict__ XW, int N)
{
    __shared__ __align__(16) float A[XAB][HH];
    int tid = threadIdx.x;
    int abase = blockIdx.x * XAB;
    for (int idx = tid; idx < XAB * HH; idx += 256) {
        int a = idx >> 7, k = idx & 127;
        A[a][k] = (abase + a < N) ? X[(size_t)(abase + a) * HH + k] : 0.f;
    }
    __syncthreads();
    int n = tid & 127, s = tid >> 7;
    float acc[16];
#pragma unroll
    for (int i = 0; i < 16; ++i) acc[i] = 0.f;
    for (int kc = 0; kc < 32; ++kc) {
        float w0 = W[(4 * kc + 0) * HH + n];
        float w1 = W[(4 * kc + 1) * HH + n];
        float w2 = W[(4 * kc + 2) * HH + n];
        float w3 = W[(4 * kc + 3) * HH + n];
#pragma unroll
        for (int i = 0; i < 16; ++i) {
            float4 av = *(const float4*)&A[s * 16 + i][4 * kc];
            acc[i] = fmaf(av.x, w0, acc[i]);
            acc[i] = fmaf(av.y, w1, acc[i]);
            acc[i] = fmaf(av.z, w2, acc[i]);
            acc[i] = fmaf(av.w, w3, acc[i]);
        }
    }
    float b = bias[n];
#pragma unroll
    for (int i = 0; i < 16; ++i) {
        int a = abase + s * 16 + i;
        if (a < N) XW[(size_t)a * HH + n] = acc[i] + b;
    }
}

// ---------------------------------------------------------------------------
// Edge pass: one wave per atom; 16-edge MFMA tiles, prefetched pipeline.
// ---------------------------------------------------------------------------
__global__ __launch_bounds__(256) void edge_mfma_kernel(
    const float* __restrict__ XW, const unsigned short* __restrict__ W1rT,
    const unsigned short* __restrict__ RBF, const int* __restrict__ rowptr,
    const int* __restrict__ ecol, float* __restrict__ S, int N)
{
    int a = (blockIdx.x << 2) + (threadIdx.x >> 6);
    int lane = threadIdx.x & 63;
    if (a >= N) return;
    int c = lane & 15, q = lane >> 4;

    // A-frags (layer weights), wave-constant: A[m=c][k=q*8+j]
    short8 Afr[8][2];
#pragma unroll
    for (int nt = 0; nt < 8; ++nt) {
        Afr[nt][0] = *(const short8*)&W1rT[(nt * 16 + c) * 64 + q * 8];
        Afr[nt][1] = *(const short8*)&W1rT[(nt * 16 + c) * 64 + 32 + q * 8];
    }

    int es = rowptr[a], ee = rowptr[a + 1];
    float acc[8][4];
#pragma unroll
    for (int nt = 0; nt < 8; ++nt)
#pragma unroll
        for (int r = 0; r < 4; ++r) acc[nt][r] = 0.f;

    short8 B0, B1; int col = 0; bool valid = false;
    if (es < ee) {  // prefetch tile 0 (wave-uniform branch)
        int e = es + c;
        valid = e < ee;
        B0 = *(const short8*)&RBF[(size_t)e * 64 + q * 8];
        B1 = *(const short8*)&RBF[(size_t)e * 64 + 32 + q * 8];
        col = ecol[valid ? e : ee - 1];
    }

    for (int eb = es; eb < ee; eb += 16) {
        short8 cB0 = B0, cB1 = B1;
        int ccol = col; bool cval = valid;
        int ebn = eb + 16;
        if (ebn < ee) {  // prefetch next tile
            int e2 = ebn + c;
            valid = e2 < ee;
            B0 = *(const short8*)&RBF[(size_t)e2 * 64 + q * 8];
            B1 = *(const short8*)&RBF[(size_t)e2 * 64 + 32 + q * 8];
            col = ecol[valid ? e2 : ee - 1];
        }
        const float* xwrow = XW + (size_t)ccol * HH;
        float4 gx[8];
#pragma unroll
        for (int nt = 0; nt < 8; ++nt)
            gx[nt] = *(const float4*)&xwrow[nt * 16 + q * 4];
        float msk = cval ? 1.f : 0.f;
#pragma unroll
        for (int nt = 0; nt < 8; ++nt) {
            floatx4 C = {0.f, 0.f, 0.f, 0.f};
            C = __builtin_amdgcn_mfma_f32_16x16x32_bf16(Afr[nt][0], cB0, C, 0, 0, 0);
            C = __builtin_amdgcn_mfma_f32_16x16x32_bf16(Afr[nt][1], cB1, C, 0, 0, 0);
            float gg[4] = {gx[nt].x, gx[nt].y, gx[nt].z, gx[nt].w};
#pragma unroll
            for (int r = 0; r < 4; ++r) {
                float h = C[r] + gg[r];
                float v = h * fast_sigmoid(h);     // silu via v_rcp, no fdiv seq
                acc[nt][r] = fmaf(v, msk, acc[nt][r]);
            }
        }
    }

    // Index-splitting butterfly over the 16 edge-classes (c bits).
    int b3 = (c >> 3) & 1, b0 = c & 1, b1 = (c >> 1) & 1, b2 = (c >> 2) & 1;
    float s16[8][2];
#pragma unroll
    for (int t = 0; t < 8; ++t)
#pragma unroll
        for (int p = 0; p < 2; ++p) {
            float keep = b3 ? acc[t][2 + p] : acc[t][p];
            float send = b3 ? acc[t][p] : acc[t][2 + p];
            s16[t][p] = keep + __shfl_xor(send, 8, 64);
        }
    float s8[4][2];
#pragma unroll
    for (int t = 0; t < 4; ++t)
#pragma unroll
        for (int p = 0; p < 2; ++p) {
            float keep = b0 ? s16[2 * t + 1][p] : s16[2 * t][p];
            float send = b0 ? s16[2 * t][p] : s16[2 * t + 1][p];
            s8[t][p] = keep + __shfl_xor(send, 1, 64);
        }
    float s4[2][2];
#pragma unroll
    for (int u = 0; u < 2; ++u)
#pragma unroll
        for (int p = 0; p < 2; ++p) {
            float keep = b1 ? s8[2 * u + 1][p] : s8[2 * u][p];
            float send = b1 ? s8[2 * u][p] : s8[2 * u + 1][p];
            s4[u][p] = keep + __shfl_xor(send, 2, 64);
        }
    float s2[2];
#pragma unroll
    for (int p = 0; p < 2; ++p) {
        float keep = b2 ? s4[1][p] : s4[0][p];
        float send = b2 ? s4[0][p] : s4[1][p];
        s2[p] = keep + __shfl_xor(send, 4, 64);
    }
    float2 st; st.x = s2[0]; st.y = s2[1];
    *(float2*)&S[(size_t)a * HH + (c & 7) * 16 + (q << 2) + (b3 << 1)] = st;
}

// GRU fused + next layer's XW: gi = S@Wc + deg*P + b_ih; X += (1-z)*n;
// then (if do_xw) XW = X_new @ Wnext + b1next for the same 16 atoms.
#define GAB 16
__global__ __launch_bounds__(256) void grux_kernel(
    const float* __restrict__ S, const float* __restrict__ Wc,
    const float* __restrict__ P, const float* __restrict__ bih,
    const float* __restrict__ bhh, const int* __restrict__ rowptr,
    float* __restrict__ X, int N,
    const float* __restrict__ Wnext, const float* __restrict__ b1next,
    float* __restrict__ XW, int do_xw)
{
    __shared__ __align__(16) float A[GAB][HH];
    int tid = threadIdx.x;
    int abase = blockIdx.x * GAB;
    for (int idx = tid; idx < GAB * HH; idx += 256) {
        int a = idx >> 7, k = idx & 127;
        A[a][k] = (abase + a < N) ? S[(size_t)(abase + a) * HH + k] : 0.f;
    }
    __syncthreads();
    int n = tid & 127, s = tid >> 7;
    float acc0[8], acc1[8], acc2[8];
#pragma unroll
    for (int i = 0; i < 8; ++i) { acc0[i] = 0.f; acc1[i] = 0.f; acc2[i] = 0.f; }
    for (int kc = 0; kc < 32; ++kc) {
        float wr[4], wz[4], wn[4];
#pragma unroll
        for (int qq = 0; qq < 4; ++qq) {
            int k = 4 * kc + qq;
            wr[qq] = Wc[(size_t)k * 384 + n];
            wz[qq] = Wc[(size_t)k * 384 + 128 + n];
            wn[qq] = Wc[(size_t)k * 384 + 256 + n];
        }
#pragma unroll
        for (int i = 0; i < 8; ++i) {
            float4 av = *(const float4*)&A[s * 8 + i][4 * kc];
            acc0[i] = fmaf(av.x, wr[0], fmaf(av.y, wr[1], fmaf(av.z, wr[2], fmaf(av.w, wr[3], acc0[i]))));
            acc1[i] = fmaf(av.x, wz[0], fmaf(av.y, wz[1], fmaf(av.z, wz[2], fmaf(av.w, wz[3], acc1[i]))));
            acc2[i] = fmaf(av.x, wn[0], fmaf(av.y, wn[1], fmaf(av.z, wn[2], fmaf(av.w, wn[3], acc2[i]))));
        }
    }
    float pr = P[n], pz = P[128 + n], pn = P[256 + n];
    float br = bih[n], bz = bih[128 + n], bn = bih[256 + n];
    float hr = bhh[n], hz = bhh[128 + n], hn = bhh[256 + n];
    float xn[8];
#pragma unroll
    for (int i = 0; i < 8; ++i) {
        int a = abase + s * 8 + i;
        xn[i] = 0.f;
        if (a >= N) continue;
        float deg = (float)(rowptr[a + 1] - rowptr[a]);
        float g0 = acc0[i] + deg * pr + br;
        float g1 = acc1[i] + deg * pz + bz;
        float g2 = acc2[i] + deg * pn + bn;
        float r = fast_sigmoid(g0 + hr);
        float z = fast_sigmoid(g1 + hz);
        float nn = fast_tanh(g2 + r * hn);
        float xo = X[(size_t)a * HH + n];
        float xv = xo + (1.f - z) * nn;
        X[(size_t)a * HH + n] = xv;
        xn[i] = xv;
    }
    __syncthreads();               // all reads of A done
#pragma unroll
    for (int i = 0; i < 8; ++i) A[s * 8 + i][n] = xn[i];
    __syncthreads();
    if (!do_xw) return;
    float acc[8];
#pragma unroll
    for (int i = 0; i < 8; ++i) acc[i] = 0.f;
    for (int kc = 0; kc < 32; ++kc) {
        float w0 = Wnext[(4 * kc + 0) * HH + n];
        float w1 = Wnext[(4 * kc + 1) * HH + n];
        float w2 = Wnext[(4 * kc + 2) * HH + n];
        float w3 = Wnext[(4 * kc + 3) * HH + n];
#pragma unroll
        for (int i = 0; i < 8; ++i) {
            float4 av = *(const float4*)&A[s * 8 + i][4 * kc];
            acc[i] = fmaf(av.x, w0, acc[i]);
            acc[i] = fmaf(av.y, w1, acc[i]);
            acc[i] = fmaf(av.z, w2, acc[i]);
            acc[i] = fmaf(av.w, w3, acc[i]);
        }
    }
    float b = b1next[n];
#pragma unroll
    for (int i = 0; i < 8; ++i) {
        int a = abase + s * 8 + i;
        if (a < N) XW[(size_t)a * HH + n] = acc[i] + b;
    }
}

// LayerNorm -> d_out x region (no atomics)
__global__ __launch_bounds__(256) void ln_kernel(
    const float* __restrict__ X, const float* __restrict__ g,
    const float* __restrict__ b, float* __restrict__ out, int N)
{
    int a = blockIdx.x * 4 + (threadIdx.x >> 6);
    int lane = threadIdx.x & 63;
    if (a >= N) return;
    float v0 = X[(size_t)a * HH + lane];
    float v1 = X[(size_t)a * HH + 64 + lane];
    float sm = v0 + v1;
    for (int off = 32; off > 0; off >>= 1) sm += __shfl_xor(sm, off, 64);
    float mu = sm * (1.f / 128.f);
    float d0 = v0 - mu, d1 = v1 - mu;
    float vq = d0 * d0 + d1 * d1;
    for (int off = 32; off > 0; off >>= 1) vq += __shfl_xor(vq, off, 64);
    float inv = rsqrtf(vq * (1.f / 128.f) + 1e-5f);
    out[(size_t)a * HH + lane] = d0 * inv * g[lane] + b[lane];
    out[(size_t)a * HH + 64 + lane] = d1 * inv * g[64 + lane] + b[64 + lane];
}

// Block-per-molecule mean pool over sorted batch segments.
__global__ __launch_bounds__(256) void pool_kernel(
    const float* __restrict__ outx, const int* __restrict__ bptr,
    float* __restrict__ outg)
{
    __shared__ float sm[256];
    int m = blockIdx.x, t = threadIdx.x;
    int n = t & 127, s = t >> 7;
    int a0 = bptr[m], a1 = bptr[m + 1];
    float acc = 0.f;
    for (int a = a0 + s; a < a1; a += 2)
        acc += outx[(size_t)a * HH + n];
    sm[t] = acc;
    __syncthreads();
    if (t < 128) {
        float cnt = (float)(a1 - a0);
        outg[(size_t)m * HH + t] = (sm[t] + sm[t + 128]) / fmaxf(cnt, 1.f);
    }
}

extern "C" void kernel_launch(void* const* d_in, const int* in_sizes, int n_in,
                              void* d_out, int out_size, void* d_ws, size_t ws_size,
                              hipStream_t stream)
{
    const int*   an   = (const int*)d_in[0];
    const float* pos  = (const float*)d_in[1];
    const int*   bat  = (const int*)d_in[2];
    const int*   eidx = (const int*)d_in[3];
    const float* emb  = (const float*)d_in[4];
    const float* W1   = (const float*)d_in[5];
    const float* b1   = (const float*)d_in[6];
    const float* W2   = (const float*)d_in[7];
    const float* b2   = (const float*)d_in[8];
    const float* Wih  = (const float*)d_in[9];
    const float* bih  = (const float*)d_in[10];
    const float* bhh  = (const float*)d_in[11];
    const float* lng  = (const float*)d_in[12];
    const float* lnb  = (const float*)d_in[13];

    int N = in_sizes[0];
    int E = in_sizes[3] / 2;
    int M = out_size / HH - N;
    int Eall = ((E + 15) & ~15) + 16;
    const int* erow = eidx;
    const int* ecol = eidx + E;

    float* ws   = (float*)d_ws;
    size_t off = 0;
    float* X    = ws + off; off += (size_t)N * HH;
    float* S    = ws + off; off += (size_t)N * HH;
    float* XW   = ws + off; off += (size_t)N * HH;
    float* Wc   = ws + off; off += (size_t)LL * HH * 384;
    float* P    = ws + off; off += LL * 384;
    int* rowptr = (int*)(ws + off); off += N + 1;
    int* bptr   = (int*)(ws + off); off += M + 1;
    off = (off + 3) & ~(size_t)3;
    unsigned short* RBF  = (unsigned short*)(ws + off); off += (size_t)Eall * 32;
    unsigned short* W1rT = (unsigned short*)(ws + off); off += (size_t)LL * HH * 32;

    float* outx = (float*)d_out;
    float* outg = outx + (size_t)N * HH;

    int PT = (E > N ? E : N);

    // one-time prep
    init_x_kernel<<<(N * HH + 255) / 256, 256, 0, stream>>>(an, emb, X, N * HH);
    ptr_kernel<<<(PT + 255) / 256, 256, 0, stream>>>(erow, rowptr, E, N, bat, bptr, M);
    rbf_kernel<<<(Eall + 255) / 256, 256, 0, stream>>>(pos, erow, ecol, RBF, E, Eall);
    w1rt_kernel<<<(LL * HH * 64 + 255) / 256, 256, 0, stream>>>(W1, W1rT);
    wc_kernel<<<LL * HH, 384, 0, stream>>>(W2, Wih, Wc);
    p_kernel<<<LL, 384, 0, stream>>>(b2, Wih, P);

    // layer 0 XW
    xw_kernel<<<(N + XAB - 1) / XAB, 256, 0, stream>>>(X, W1, b1, XW, N);

    int edge_blocks = (N + 3) / 4;
    for (int l = 0; l < LL; ++l) {
        edge_mfma_kernel<<<edge_blocks, 256, 0, stream>>>(
            XW, W1rT + (size_t)l * HH * 64, RBF, rowptr, ecol, S, N);
        int do_xw = (l < LL - 1) ? 1 : 0;
        const float* Wnext = W1 + (size_t)(l + 1 < LL ? l + 1 : l) * 178 * HH;
        const float* bnext = b1 + (size_t)(l + 1 < LL ? l + 1 : l) * HH;
        grux_kernel<<<(N + GAB - 1) / GAB, 256, 0, stream>>>(
            S, Wc + (size_t)l * HH * 384, P + l * 384,
            bih + l * 384, bhh + l * 384, rowptr, X, N,
            Wnext, bnext, XW, do_xw);
    }

    ln_kernel<<<(N + 3) / 4, 256, 0, stream>>>(X, lng, lnb, outx, N);
    pool_kernel<<<M, 256, 0, stream>>>(outx, bptr, outg);
}

// Round 4
// 491.425 us; speedup vs baseline: 1.5956x; 1.0204x over previous
//
#include <hip/hip_runtime.h>
#include <hip/hip_bf16.h>
#include <math.h>

// ---------------------------------------------------------------------------
// InfomaxEncoder, round 4:
//  - edge: rbf computed IN-REGISTER from dist (no 41MB RBF stream), 3-stage
//    index pipeline (ecol/dist 2 tiles ahead -> XW gather issues at tile
//    start), XW folded into MFMA accumulator init.
//  - ln/pool without atomics; gru(l) fused with xw(l+1).
// Factorizations (exact): XW = X@W1_x + b1; S = segsum silu(XW[col] + rbf@W1r)
// over sorted rows; gi = S@Wc + deg*P + b_ih, Wc = W2@W_ih, P = b2@W_ih.
// ---------------------------------------------------------------------------

#define HH 128
#define RR 50
#define LL 4

typedef __attribute__((ext_vector_type(8))) short short8;
typedef __attribute__((ext_vector_type(4))) float floatx4;

__device__ __forceinline__ unsigned short f2bf(float f) {
    unsigned u = __float_as_uint(f);
    unsigned r = (u + 0x7fffu + ((u >> 16) & 1u)) >> 16;
    return (unsigned short)r;
}
__device__ __forceinline__ float fast_sigmoid(float x) {
    return __builtin_amdgcn_rcpf(1.f + __expf(-x));
}
__device__ __forceinline__ float fast_tanh(float x) {
    x = fminf(fmaxf(x, -15.f), 15.f);
    float t = __expf(2.f * x);
    return (t - 1.f) * __builtin_amdgcn_rcpf(t + 1.f);
}

__global__ __launch_bounds__(256) void init_x_kernel(
    const int* __restrict__ an, const float* __restrict__ emb,
    float* __restrict__ X, int count)
{
    int g = blockIdx.x * 256 + threadIdx.x;
    if (g >= count) return;
    int i = g >> 7, n = g & 127;
    int z = an[i];
    z = z < 0 ? 0 : (z > 99 ? 99 : z);
    X[g] = emb[z * HH + n];
}

// rowptr from sorted erow; bptr from sorted batch (both in one kernel)
__global__ __launch_bounds__(256) void ptr_kernel(
    const int* __restrict__ erow, int* __restrict__ rowptr, int E, int N,
    const int* __restrict__ batch, int* __restrict__ bptr, int M)
{
    int i = blockIdx.x * 256 + threadIdx.x;
    if (i < E) {
        int rc = erow[i];
        int rp = (i > 0) ? erow[i - 1] : -1;
        for (int r = rp + 1; r <= rc; ++r) rowptr[r] = i;
        if (i == E - 1)
            for (int r = rc + 1; r <= N; ++r) rowptr[r] = E;
    }
    if (i < N) {
        int bc = batch[i];
        int bp = (i > 0) ? batch[i - 1] : -1;
        for (int m = bp + 1; m <= bc; ++m) bptr[m] = i;
        if (i == N - 1)
            for (int m = bc + 1; m <= M; ++m) bptr[m] = N;
    }
}

// dist[e] = |pos[row]-pos[col]|
__global__ __launch_bounds__(256) void dist_kernel(
    const float* __restrict__ pos, const int* __restrict__ erow,
    const int* __restrict__ ecol, float* __restrict__ dist, int E)
{
    int e = blockIdx.x * 256 + threadIdx.x;
    if (e >= E) return;
    int r = erow[e], c = ecol[e];
    float dx = pos[r * 3 + 0] - pos[c * 3 + 0];
    float dy = pos[r * 3 + 1] - pos[c * 3 + 1];
    float dz = pos[r * 3 + 2] - pos[c * 3 + 2];
    dist[e] = sqrtf(dx * dx + dy * dy + dz * dz);
}

// W1rT_bf16[L][128n][64k]
__global__ __launch_bounds__(256) void w1rt_kernel(
    const float* __restrict__ W1, unsigned short* __restrict__ W1rT)
{
    int idx = blockIdx.x * 256 + threadIdx.x;
    if (idx >= LL * HH * 64) return;
    int l = idx >> 13, rem = idx & 8191, n = rem >> 6, k = rem & 63;
    float v = (k < RR) ? W1[((size_t)l * 178 + 128 + k) * HH + n] : 0.f;
    W1rT[idx] = f2bf(v);
}

// Wc[l][i][j] = sum_k W2[l][i][k] * W_ih[l][k][j]
__global__ __launch_bounds__(384) void wc_kernel(
    const float* __restrict__ W2, const float* __restrict__ Wih,
    float* __restrict__ Wc)
{
    int l = blockIdx.x >> 7, i = blockIdx.x & 127, j = threadIdx.x;
    const float* w2row = W2 + ((size_t)l * HH + i) * HH;
    const float* wih = Wih + (size_t)l * HH * 384;
    float acc = 0.f;
#pragma unroll 4
    for (int k = 0; k < HH; ++k)
        acc = fmaf(w2row[k], wih[(size_t)k * 384 + j], acc);
    Wc[((size_t)l * HH + i) * 384 + j] = acc;
}

// P[l][j] = sum_k b2[l][k] * W_ih[l][k][j]
__global__ __launch_bounds__(384) void p_kernel(
    const float* __restrict__ b2, const float* __restrict__ Wih,
    float* __restrict__ P)
{
    int l = blockIdx.x, j = threadIdx.x;
    const float* b2l = b2 + (size_t)l * HH;
    const float* wih = Wih + (size_t)l * HH * 384;
    float acc = 0.f;
#pragma unroll 4
    for (int k = 0; k < HH; ++k)
        acc = fmaf(b2l[k], wih[(size_t)k * 384 + j], acc);
    P[l * 384 + j] = acc;
}

// XW = X @ W1_x + b1 (layer 0 only; later layers fused into grux)
#define XAB 32
__global__ __launch_bounds__(256) void xw_kernel(
    const float* __restrict__ X, const float* __restrict__ W,
    const float* __restrict__ bias, float* __restrict__ XW, int N)
{
    __shared__ __align__(16) float A[XAB][HH];
    int tid = threadIdx.x;
    int abase = blockIdx.x * XAB;
    for (int idx = tid; idx < XAB * HH; idx += 256) {
        int a = idx >> 7, k = idx & 127;
        A[a][k] = (abase + a < N) ? X[(size_t)(abase + a) * HH + k] : 0.f;
    }
    __syncthreads();
    int n = tid & 127, s = tid >> 7;
    float acc[16];
#pragma unroll
    for (int i = 0; i < 16; ++i) acc[i] = 0.f;
    for (int kc = 0; kc < 32; ++kc) {
        float w0 = W[(4 * kc + 0) * HH + n];
        float w1 = W[(4 * kc + 1) * HH + n];
        float w2 = W[(4 * kc + 2) * HH + n];
        float w3 = W[(4 * kc + 3) * HH + n];
#pragma unroll
        for (int i = 0; i < 16; ++i) {
            float4 av = *(const float4*)&A[s * 16 + i][4 * kc];
            acc[i] = fmaf(av.x, w0, acc[i]);
            acc[i] = fmaf(av.y, w1, acc[i]);
            acc[i] = fmaf(av.z, w2, acc[i]);
            acc[i] = fmaf(av.w, w3, acc[i]);
        }
    }
    float b = bias[n];
#pragma unroll
    for (int i = 0; i < 16; ++i) {
        int a = abase + s * 16 + i;
        if (a < N) XW[(size_t)a * HH + n] = acc[i] + b;
    }
}

// ---------------------------------------------------------------------------
// Edge pass: wave per atom; 16-edge MFMA tiles; rbf in-register from dist;
// ecol/dist prefetched 2 tiles ahead so XW gathers issue at tile start.
// ---------------------------------------------------------------------------
__global__ __launch_bounds__(256) void edge_mfma_kernel(
    const float* __restrict__ XW, const unsigned short* __restrict__ W1rT,
    const float* __restrict__ dist, const int* __restrict__ rowptr,
    const int* __restrict__ ecol, float* __restrict__ S, int N)
{
    int a = (blockIdx.x << 2) + (threadIdx.x >> 6);
    int lane = threadIdx.x & 63;
    if (a >= N) return;
    int c = lane & 15, q = lane >> 4;

    // A-frags (layer weights), wave-constant: A[m=c][k=q*8+j]
    short8 Afr[8][2];
#pragma unroll
    for (int nt = 0; nt < 8; ++nt) {
        Afr[nt][0] = *(const short8*)&W1rT[(nt * 16 + c) * 64 + q * 8];
        Afr[nt][1] = *(const short8*)&W1rT[(nt * 16 + c) * 64 + 32 + q * 8];
    }

    int es = rowptr[a], ee = rowptr[a + 1];
    float acc[8][4];
#pragma unroll
    for (int nt = 0; nt < 8; ++nt)
#pragma unroll
        for (int r = 0; r < 4; ++r) acc[nt][r] = 0.f;

    if (es < ee) {
        const float stepc = 5.0f / 49.0f;
        int last = ee - 1;
        // stage 0 (tile 0) and stage 1 (tile 1) index loads
        int ce0 = es + c;        if (ce0 > last) ce0 = last;
        float dcur = dist[ce0];
        int  colcur = ecol[ce0];
        int ce1 = es + 16 + c;   if (ce1 > last) ce1 = last;
        float dnxt = dist[ce1];
        int  colnxt = ecol[ce1];

        for (int eb = es; eb < ee; eb += 16) {
            // XW gathers for current tile (col ready from 2-ahead prefetch)
            const float* xwrow = XW + (size_t)colcur * HH;
            float4 gx[8];
#pragma unroll
            for (int nt = 0; nt < 8; ++nt)
                gx[nt] = *(const float4*)&xwrow[nt * 16 + (q << 2)];

            float d_t = dcur;
            // rotate pipeline; issue tile+2 index loads
            dcur = dnxt; colcur = colnxt;
            int ce2 = eb + 32 + c; if (ce2 > last) ce2 = last;
            dnxt = dist[ce2];
            colnxt = ecol[ce2];

            // B-frags from d_t (overlaps gx latency): k = half*32 + q*8 + j
            union { unsigned u[4]; short8 s; } ub0, ub1;
            float dq = d_t - (float)(q << 3) * stepc;
#pragma unroll
            for (int p = 0; p < 4; ++p) {
                float t0 = dq - (float)(2 * p) * stepc;
                float t1 = dq - (float)(2 * p + 1) * stepc;
                float r0 = __expf(-50.f * t0 * t0);
                float r1 = __expf(-50.f * t1 * t1);
                ub0.u[p] = (unsigned)f2bf(r0) | ((unsigned)f2bf(r1) << 16);
                float t2 = dq - (float)(32 + 2 * p) * stepc;
                float t3 = dq - (float)(32 + 2 * p + 1) * stepc;
                float r2 = __expf(-50.f * t2 * t2);
                float r3 = __expf(-50.f * t3 * t3);
                ub1.u[p] = (unsigned)f2bf(r2) | ((unsigned)f2bf(r3) << 16);
            }
            short8 B0 = ub0.s, B1 = ub1.s;
            float msk = ((eb + c) < ee) ? 1.f : 0.f;

#pragma unroll
            for (int nt = 0; nt < 8; ++nt) {
                floatx4 C = {gx[nt].x, gx[nt].y, gx[nt].z, gx[nt].w};
                C = __builtin_amdgcn_mfma_f32_16x16x32_bf16(Afr[nt][0], B0, C, 0, 0, 0);
                C = __builtin_amdgcn_mfma_f32_16x16x32_bf16(Afr[nt][1], B1, C, 0, 0, 0);
#pragma unroll
                for (int r = 0; r < 4; ++r) {
                    float h = C[r];
                    float v = h * fast_sigmoid(h);   // silu
                    acc[nt][r] = fmaf(v, msk, acc[nt][r]);
                }
            }
        }
    }

    // Index-splitting butterfly over the 16 edge-classes (c bits).
    int b3 = (c >> 3) & 1, b0 = c & 1, b1 = (c >> 1) & 1, b2 = (c >> 2) & 1;
    float s16[8][2];
#pragma unroll
    for (int t = 0; t < 8; ++t)
#pragma unroll
        for (int p = 0; p < 2; ++p) {
            float keep = b3 ? acc[t][2 + p] : acc[t][p];
            float send = b3 ? acc[t][p] : acc[t][2 + p];
            s16[t][p] = keep + __shfl_xor(send, 8, 64);
        }
    float s8[4][2];
#pragma unroll
    for (int t = 0; t < 4; ++t)
#pragma unroll
        for (int p = 0; p < 2; ++p) {
            float keep = b0 ? s16[2 * t + 1][p] : s16[2 * t][p];
            float send = b0 ? s16[2 * t][p] : s16[2 * t + 1][p];
            s8[t][p] = keep + __shfl_xor(send, 1, 64);
        }
    float s4[2][2];
#pragma unroll
    for (int u = 0; u < 2; ++u)
#pragma unroll
        for (int p = 0; p < 2; ++p) {
            float keep = b1 ? s8[2 * u + 1][p] : s8[2 * u][p];
            float send = b1 ? s8[2 * u][p] : s8[2 * u + 1][p];
            s4[u][p] = keep + __shfl_xor(send, 2, 64);
        }
    float s2[2];
#pragma unroll
    for (int p = 0; p < 2; ++p) {
        float keep = b2 ? s4[1][p] : s4[0][p];
        float send = b2 ? s4[0][p] : s4[1][p];
        s2[p] = keep + __shfl_xor(send, 4, 64);
    }
    float2 st; st.x = s2[0]; st.y = s2[1];
    *(float2*)&S[(size_t)a * HH + (c & 7) * 16 + (q << 2) + (b3 << 1)] = st;
}

// GRU fused + next layer's XW: gi = S@Wc + deg*P + b_ih; X += (1-z)*n;
// then (if do_xw) XW = X_new @ Wnext + b1next for the same 16 atoms.
#define GAB 16
__global__ __launch_bounds__(256) void grux_kernel(
    const float* __restrict__ S, const float* __restrict__ Wc,
    const float* __restrict__ P, const float* __restrict__ bih,
    const float* __restrict__ bhh, const int* __restrict__ rowptr,
    float* __restrict__ X, int N,
    const float* __restrict__ Wnext, const float* __restrict__ b1next,
    float* __restrict__ XW, int do_xw)
{
    __shared__ __align__(16) float A[GAB][HH];
    int tid = threadIdx.x;
    int abase = blockIdx.x * GAB;
    for (int idx = tid; idx < GAB * HH; idx += 256) {
        int a = idx >> 7, k = idx & 127;
        A[a][k] = (abase + a < N) ? S[(size_t)(abase + a) * HH + k] : 0.f;
    }
    __syncthreads();
    int n = tid & 127, s = tid >> 7;
    float acc0[8], acc1[8], acc2[8];
#pragma unroll
    for (int i = 0; i < 8; ++i) { acc0[i] = 0.f; acc1[i] = 0.f; acc2[i] = 0.f; }
    for (int kc = 0; kc < 32; ++kc) {
        float wr[4], wz[4], wn[4];
#pragma unroll
        for (int qq = 0; qq < 4; ++qq) {
            int k = 4 * kc + qq;
            wr[qq] = Wc[(size_t)k * 384 + n];
            wz[qq] = Wc[(size_t)k * 384 + 128 + n];
            wn[qq] = Wc[(size_t)k * 384 + 256 + n];
        }
#pragma unroll
        for (int i = 0; i < 8; ++i) {
            float4 av = *(const float4*)&A[s * 8 + i][4 * kc];
            acc0[i] = fmaf(av.x, wr[0], fmaf(av.y, wr[1], fmaf(av.z, wr[2], fmaf(av.w, wr[3], acc0[i]))));
            acc1[i] = fmaf(av.x, wz[0], fmaf(av.y, wz[1], fmaf(av.z, wz[2], fmaf(av.w, wz[3], acc1[i]))));
            acc2[i] = fmaf(av.x, wn[0], fmaf(av.y, wn[1], fmaf(av.z, wn[2], fmaf(av.w, wn[3], acc2[i]))));
        }
    }
    float pr = P[n], pz = P[128 + n], pn = P[256 + n];
    float br = bih[n], bz = bih[128 + n], bn = bih[256 + n];
    float hr = bhh[n], hz = bhh[128 + n], hn = bhh[256 + n];
    float xn[8];
#pragma unroll
    for (int i = 0; i < 8; ++i) {
        int a = abase + s * 8 + i;
        xn[i] = 0.f;
        if (a >= N) continue;
        float deg = (float)(rowptr[a + 1] - rowptr[a]);
        float g0 = acc0[i] + deg * pr + br;
        float g1 = acc1[i] + deg * pz + bz;
        float g2 = acc2[i] + deg * pn + bn;
        float r = fast_sigmoid(g0 + hr);
        float z = fast_sigmoid(g1 + hz);
        float nn = fast_tanh(g2 + r * hn);
        float xo = X[(size_t)a * HH + n];
        float xv = xo + (1.f - z) * nn;
        X[(size_t)a * HH + n] = xv;
        xn[i] = xv;
    }
    __syncthreads();               // all reads of A done
#pragma unroll
    for (int i = 0; i < 8; ++i) A[s * 8 + i][n] = xn[i];
    __syncthreads();
    if (!do_xw) return;
    float acc[8];
#pragma unroll
    for (int i = 0; i < 8; ++i) acc[i] = 0.f;
    for (int kc = 0; kc < 32; ++kc) {
        float w0 = Wnext[(4 * kc + 0) * HH + n];
        float w1 = Wnext[(4 * kc + 1) * HH + n];
        float w2 = Wnext[(4 * kc + 2) * HH + n];
        float w3 = Wnext[(4 * kc + 3) * HH + n];
#pragma unroll
        for (int i = 0; i < 8; ++i) {
            float4 av = *(const float4*)&A[s * 8 + i][4 * kc];
            acc[i] = fmaf(av.x, w0, acc[i]);
            acc[i] = fmaf(av.y, w1, acc[i]);
            acc[i] = fmaf(av.z, w2, acc[i]);
            acc[i] = fmaf(av.w, w3, acc[i]);
        }
    }
    float b = b1next[n];
#pragma unroll
    for (int i = 0; i < 8; ++i) {
        int a = abase + s * 8 + i;
        if (a < N) XW[(size_t)a * HH + n] = acc[i] + b;
    }
}

// LayerNorm -> d_out x region (no atomics)
__global__ __launch_bounds__(256) void ln_kernel(
    const float* __restrict__ X, const float* __restrict__ g,
    const float* __restrict__ b, float* __restrict__ out, int N)
{
    int a = blockIdx.x * 4 + (threadIdx.x >> 6);
    int lane = threadIdx.x & 63;
    if (a >= N) return;
    float v0 = X[(size_t)a * HH + lane];
    float v1 = X[(size_t)a * HH + 64 + lane];
    float sm = v0 + v1;
    for (int off = 32; off > 0; off >>= 1) sm += __shfl_xor(sm, off, 64);
    float mu = sm * (1.f / 128.f);
    float d0 = v0 - mu, d1 = v1 - mu;
    float vq = d0 * d0 + d1 * d1;
    for (int off = 32; off > 0; off >>= 1) vq += __shfl_xor(vq, off, 64);
    float inv = rsqrtf(vq * (1.f / 128.f) + 1e-5f);
    out[(size_t)a * HH + lane] = d0 * inv * g[lane] + b[lane];
    out[(size_t)a * HH + 64 + lane] = d1 * inv * g[64 + lane] + b[64 + lane];
}

// Block-per-molecule mean pool over sorted batch segments.
__global__ __launch_bounds__(256) void pool_kernel(
    const float* __restrict__ outx, const int* __restrict__ bptr,
    float* __restrict__ outg)
{
    __shared__ float sm[256];
    int m = blockIdx.x, t = threadIdx.x;
    int n = t & 127, s = t >> 7;
    int a0 = bptr[m], a1 = bptr[m + 1];
    float acc = 0.f;
    for (int a = a0 + s; a < a1; a += 2)
        acc += outx[(size_t)a * HH + n];
    sm[t] = acc;
    __syncthreads();
    if (t < 128) {
        float cnt = (float)(a1 - a0);
        outg[(size_t)m * HH + t] = (sm[t] + sm[t + 128]) / fmaxf(cnt, 1.f);
    }
}

extern "C" void kernel_launch(void* const* d_in, const int* in_sizes, int n_in,
                              void* d_out, int out_size, void* d_ws, size_t ws_size,
                              hipStream_t stream)
{
    const int*   an   = (const int*)d_in[0];
    const float* pos  = (const float*)d_in[1];
    const int*   bat  = (const int*)d_in[2];
    const int*   eidx = (const int*)d_in[3];
    const float* emb  = (const float*)d_in[4];
    const float* W1   = (const float*)d_in[5];
    const float* b1   = (const float*)d_in[6];
    const float* W2   = (const float*)d_in[7];
    const float* b2   = (const float*)d_in[8];
    const float* Wih  = (const float*)d_in[9];
    const float* bih  = (const float*)d_in[10];
    const float* bhh  = (const float*)d_in[11];
    const float* lng  = (const float*)d_in[12];
    const float* lnb  = (const float*)d_in[13];

    int N = in_sizes[0];
    int E = in_sizes[3] / 2;
    int M = out_size / HH - N;
    const int* erow = eidx;
    const int* ecol = eidx + E;

    float* ws   = (float*)d_ws;
    size_t off = 0;
    float* X    = ws + off; off += (size_t)N * HH;
    float* S    = ws + off; off += (size_t)N * HH;
    float* XW   = ws + off; off += (size_t)N * HH;
    float* Wc   = ws + off; off += (size_t)LL * HH * 384;
    float* P    = ws + off; off += LL * 384;
    float* dist = ws + off; off += E;
    int* rowptr = (int*)(ws + off); off += N + 1;
    int* bptr   = (int*)(ws + off); off += M + 1;
    off = (off + 3) & ~(size_t)3;
    unsigned short* W1rT = (unsigned short*)(ws + off); off += (size_t)LL * HH * 32;

    float* outx = (float*)d_out;
    float* outg = outx + (size_t)N * HH;

    int PT = (E > N ? E : N);

    // one-time prep
    init_x_kernel<<<(N * HH + 255) / 256, 256, 0, stream>>>(an, emb, X, N * HH);
    ptr_kernel<<<(PT + 255) / 256, 256, 0, stream>>>(erow, rowptr, E, N, bat, bptr, M);
    dist_kernel<<<(E + 255) / 256, 256, 0, stream>>>(pos, erow, ecol, dist, E);
    w1rt_kernel<<<(LL * HH * 64 + 255) / 256, 256, 0, stream>>>(W1, W1rT);
    wc_kernel<<<LL * HH, 384, 0, stream>>>(W2, Wih, Wc);
    p_kernel<<<LL, 384, 0, stream>>>(b2, Wih, P);

    // layer 0 XW
    xw_kernel<<<(N + XAB - 1) / XAB, 256, 0, stream>>>(X, W1, b1, XW, N);

    int edge_blocks = (N + 3) / 4;
    for (int l = 0; l < LL; ++l) {
        edge_mfma_kernel<<<edge_blocks, 256, 0, stream>>>(
            XW, W1rT + (size_t)l * HH * 64, dist, rowptr, ecol, S, N);
        int do_xw = (l < LL - 1) ? 1 : 0;
        const float* Wnext = W1 + (size_t)(l + 1 < LL ? l + 1 : l) * 178 * HH;
        const float* bnext = b1 + (size_t)(l + 1 < LL ? l + 1 : l) * HH;
        grux_kernel<<<(N + GAB - 1) / GAB, 256, 0, stream>>>(
            S, Wc + (size_t)l * HH * 384, P + l * 384,
            bih + l * 384, bhh + l * 384, rowptr, X, N,
            Wnext, bnext, XW, do_xw);
    }

    ln_kernel<<<(N + 3) / 4, 256, 0, stream>>>(X, lng, lnb, outx, N);
    pool_kernel<<<M, 256, 0, stream>>>(outx, bptr, outg);
}

// Round 5
// 461.320 us; speedup vs baseline: 1.6998x; 1.0653x over previous
//
#include <hip/hip_runtime.h>
#include <hip/hip_bf16.h>
#include <math.h>

// ---------------------------------------------------------------------------
// InfomaxEncoder, round 5:
//  - grux rewritten as bf16 MFMA: S@Wc (3 gates) + fused next-layer XW,
//    operands staged bf16 (LDS pad 132 to break bank-stride), fp32 accum.
//  - WcT/W1xT precomputed in B-frag-friendly [n][k] bf16 layout.
//  - edge: XW add moved post-MFMA (C=0 init) to hide gather latency.
// Factorizations (exact): XW = X@W1_x + b1; S = segsum silu(XW[col] + rbf@W1r)
// over sorted rows; gi = S@Wc + deg*P + b_ih, Wc = W2@W_ih, P = b2@W_ih.
// ---------------------------------------------------------------------------

#define HH 128
#define RR 50
#define LL 4

typedef __attribute__((ext_vector_type(8))) short short8;
typedef __attribute__((ext_vector_type(4))) float floatx4;

__device__ __forceinline__ unsigned short f2bf(float f) {
    unsigned u = __float_as_uint(f);
    unsigned r = (u + 0x7fffu + ((u >> 16) & 1u)) >> 16;
    return (unsigned short)r;
}
__device__ __forceinline__ float fast_sigmoid(float x) {
    return __builtin_amdgcn_rcpf(1.f + __expf(-x));
}
__device__ __forceinline__ float fast_tanh(float x) {
    x = fminf(fmaxf(x, -15.f), 15.f);
    float t = __expf(2.f * x);
    return (t - 1.f) * __builtin_amdgcn_rcpf(t + 1.f);
}

__global__ __launch_bounds__(256) void init_x_kernel(
    const int* __restrict__ an, const float* __restrict__ emb,
    float* __restrict__ X, int count)
{
    int g = blockIdx.x * 256 + threadIdx.x;
    if (g >= count) return;
    int i = g >> 7, n = g & 127;
    int z = an[i];
    z = z < 0 ? 0 : (z > 99 ? 99 : z);
    X[g] = emb[z * HH + n];
}

// rowptr from sorted erow; bptr from sorted batch
__global__ __launch_bounds__(256) void ptr_kernel(
    const int* __restrict__ erow, int* __restrict__ rowptr, int E, int N,
    const int* __restrict__ batch, int* __restrict__ bptr, int M)
{
    int i = blockIdx.x * 256 + threadIdx.x;
    if (i < E) {
        int rc = erow[i];
        int rp = (i > 0) ? erow[i - 1] : -1;
        for (int r = rp + 1; r <= rc; ++r) rowptr[r] = i;
        if (i == E - 1)
            for (int r = rc + 1; r <= N; ++r) rowptr[r] = E;
    }
    if (i < N) {
        int bc = batch[i];
        int bp = (i > 0) ? batch[i - 1] : -1;
        for (int m = bp + 1; m <= bc; ++m) bptr[m] = i;
        if (i == N - 1)
            for (int m = bc + 1; m <= M; ++m) bptr[m] = N;
    }
}

// dist[e] = |pos[row]-pos[col]|
__global__ __launch_bounds__(256) void dist_kernel(
    const float* __restrict__ pos, const int* __restrict__ erow,
    const int* __restrict__ ecol, float* __restrict__ dist, int E)
{
    int e = blockIdx.x * 256 + threadIdx.x;
    if (e >= E) return;
    int r = erow[e], c = ecol[e];
    float dx = pos[r * 3 + 0] - pos[c * 3 + 0];
    float dy = pos[r * 3 + 1] - pos[c * 3 + 1];
    float dz = pos[r * 3 + 2] - pos[c * 3 + 2];
    dist[e] = sqrtf(dx * dx + dy * dy + dz * dz);
}

// W1rT_bf16[L][128n][64k] for edge-pass A-frags
__global__ __launch_bounds__(256) void w1rt_kernel(
    const float* __restrict__ W1, unsigned short* __restrict__ W1rT)
{
    int idx = blockIdx.x * 256 + threadIdx.x;
    if (idx >= LL * HH * 64) return;
    int l = idx >> 13, rem = idx & 8191, n = rem >> 6, k = rem & 63;
    float v = (k < RR) ? W1[((size_t)l * 178 + 128 + k) * HH + n] : 0.f;
    W1rT[idx] = f2bf(v);
}

// W1xT_bf16[L][128n][128k] = W1[l][k][n]  (B-frag layout for XW GEMM)
__global__ __launch_bounds__(256) void w1xt_kernel(
    const float* __restrict__ W1, unsigned short* __restrict__ W1xT)
{
    int idx = blockIdx.x * 256 + threadIdx.x;
    if (idx >= LL * HH * HH) return;
    int l = idx >> 14, rem = idx & 16383, n = rem >> 7, k = rem & 127;
    W1xT[idx] = f2bf(W1[((size_t)l * 178 + k) * HH + n]);
}

// WcT_bf16[l][384n][128k]: WcT[l][j][i] = sum_t W2[l][i][t]*Wih[l][t][j]
__global__ __launch_bounds__(384) void wc_kernel(
    const float* __restrict__ W2, const float* __restrict__ Wih,
    unsigned short* __restrict__ WcT)
{
    int l = blockIdx.x >> 7, i = blockIdx.x & 127, j = threadIdx.x;
    const float* w2row = W2 + ((size_t)l * HH + i) * HH;
    const float* wih = Wih + (size_t)l * HH * 384;
    float acc = 0.f;
#pragma unroll 4
    for (int k = 0; k < HH; ++k)
        acc = fmaf(w2row[k], wih[(size_t)k * 384 + j], acc);
    WcT[((size_t)l * 384 + j) * HH + i] = f2bf(acc);
}

// P[l][j] = sum_k b2[l][k] * W_ih[l][k][j]
__global__ __launch_bounds__(384) void p_kernel(
    const float* __restrict__ b2, const float* __restrict__ Wih,
    float* __restrict__ P)
{
    int l = blockIdx.x, j = threadIdx.x;
    const float* b2l = b2 + (size_t)l * HH;
    const float* wih = Wih + (size_t)l * HH * 384;
    float acc = 0.f;
#pragma unroll 4
    for (int k = 0; k < HH; ++k)
        acc = fmaf(b2l[k], wih[(size_t)k * 384 + j], acc);
    P[l * 384 + j] = acc;
}

// XW = X @ W1_x + b1 (layer 0 only; later layers fused into grux_mfma)
#define XAB 32
__global__ __launch_bounds__(256) void xw_kernel(
    const float* __restrict__ X, const float* __restrict__ W,
    const float* __restrict__ bias, float* __restrict__ XW, int N)
{
    __shared__ __align__(16) float A[XAB][HH];
    int tid = threadIdx.x;
    int abase = blockIdx.x * XAB;
    for (int idx = tid; idx < XAB * HH; idx += 256) {
        int a = idx >> 7, k = idx & 127;
        A[a][k] = (abase + a < N) ? X[(size_t)(abase + a) * HH + k] : 0.f;
    }
    __syncthreads();
    int n = tid & 127, s = tid >> 7;
    float acc[16];
#pragma unroll
    for (int i = 0; i < 16; ++i) acc[i] = 0.f;
    for (int kc = 0; kc < 32; ++kc) {
        float w0 = W[(4 * kc + 0) * HH + n];
        float w1 = W[(4 * kc + 1) * HH + n];
        float w2 = W[(4 * kc + 2) * HH + n];
        float w3 = W[(4 * kc + 3) * HH + n];
#pragma unroll
        for (int i = 0; i < 16; ++i) {
            float4 av = *(const float4*)&A[s * 16 + i][4 * kc];
            acc[i] = fmaf(av.x, w0, acc[i]);
            acc[i] = fmaf(av.y, w1, acc[i]);
            acc[i] = fmaf(av.z, w2, acc[i]);
            acc[i] = fmaf(av.w, w3, acc[i]);
        }
    }
    float b = bias[n];
#pragma unroll
    for (int i = 0; i < 16; ++i) {
        int a = abase + s * 16 + i;
        if (a < N) XW[(size_t)a * HH + n] = acc[i] + b;
    }
}

// ---------------------------------------------------------------------------
// Edge pass: wave per atom; 16-edge MFMA tiles; rbf in-register from dist;
// indices prefetched 2 tiles ahead; XW gather consumed AFTER the MFMAs.
// ---------------------------------------------------------------------------
__global__ __launch_bounds__(256) void edge_mfma_kernel(
    const float* __restrict__ XW, const unsigned short* __restrict__ W1rT,
    const float* __restrict__ dist, const int* __restrict__ rowptr,
    const int* __restrict__ ecol, float* __restrict__ S, int N)
{
    int a = (blockIdx.x << 2) + (threadIdx.x >> 6);
    int lane = threadIdx.x & 63;
    if (a >= N) return;
    int c = lane & 15, q = lane >> 4;

    short8 Afr[8][2];
#pragma unroll
    for (int nt = 0; nt < 8; ++nt) {
        Afr[nt][0] = *(const short8*)&W1rT[(nt * 16 + c) * 64 + q * 8];
        Afr[nt][1] = *(const short8*)&W1rT[(nt * 16 + c) * 64 + 32 + q * 8];
    }

    int es = rowptr[a], ee = rowptr[a + 1];
    float acc[8][4];
#pragma unroll
    for (int nt = 0; nt < 8; ++nt)
#pragma unroll
        for (int r = 0; r < 4; ++r) acc[nt][r] = 0.f;

    if (es < ee) {
        const float stepc = 5.0f / 49.0f;
        int last = ee - 1;
        int ce0 = es + c;        if (ce0 > last) ce0 = last;
        float dcur = dist[ce0];
        int  colcur = ecol[ce0];
        int ce1 = es + 16 + c;   if (ce1 > last) ce1 = last;
        float dnxt = dist[ce1];
        int  colnxt = ecol[ce1];

        for (int eb = es; eb < ee; eb += 16) {
            // XW gathers issued at tile start, consumed post-MFMA
            const float* xwrow = XW + (size_t)colcur * HH;
            float4 gx[8];
#pragma unroll
            for (int nt = 0; nt < 8; ++nt)
                gx[nt] = *(const float4*)&xwrow[nt * 16 + (q << 2)];

            float d_t = dcur;
            dcur = dnxt; colcur = colnxt;
            int ce2 = eb + 32 + c; if (ce2 > last) ce2 = last;
            dnxt = dist[ce2];
            colnxt = ecol[ce2];

            union { unsigned u[4]; short8 s; } ub0, ub1;
            float dq = d_t - (float)(q << 3) * stepc;
#pragma unroll
            for (int p = 0; p < 4; ++p) {
                float t0 = dq - (float)(2 * p) * stepc;
                float t1 = dq - (float)(2 * p + 1) * stepc;
                float r0 = __expf(-50.f * t0 * t0);
                float r1 = __expf(-50.f * t1 * t1);
                ub0.u[p] = (unsigned)f2bf(r0) | ((unsigned)f2bf(r1) << 16);
                float t2 = dq - (float)(32 + 2 * p) * stepc;
                float t3 = dq - (float)(32 + 2 * p + 1) * stepc;
                float r2 = __expf(-50.f * t2 * t2);
                float r3 = __expf(-50.f * t3 * t3);
                ub1.u[p] = (unsigned)f2bf(r2) | ((unsigned)f2bf(r3) << 16);
            }
            short8 B0 = ub0.s, B1 = ub1.s;
            float msk = ((eb + c) < ee) ? 1.f : 0.f;

            floatx4 C[8];
#pragma unroll
            for (int nt = 0; nt < 8; ++nt) {
                C[nt] = floatx4{0.f, 0.f, 0.f, 0.f};
                C[nt] = __builtin_amdgcn_mfma_f32_16x16x32_bf16(Afr[nt][0], B0, C[nt], 0, 0, 0);
                C[nt] = __builtin_amdgcn_mfma_f32_16x16x32_bf16(Afr[nt][1], B1, C[nt], 0, 0, 0);
            }
#pragma unroll
            for (int nt = 0; nt < 8; ++nt) {
                float gg[4] = {gx[nt].x, gx[nt].y, gx[nt].z, gx[nt].w};
#pragma unroll
                for (int r = 0; r < 4; ++r) {
                    float h = C[nt][r] + gg[r];
                    float v = h * fast_sigmoid(h);   // silu
                    acc[nt][r] = fmaf(v, msk, acc[nt][r]);
                }
            }
        }
    }

    // Index-splitting butterfly over the 16 edge-classes (c bits).
    int b3 = (c >> 3) & 1, b0 = c & 1, b1 = (c >> 1) & 1, b2 = (c >> 2) & 1;
    float s16[8][2];
#pragma unroll
    for (int t = 0; t < 8; ++t)
#pragma unroll
        for (int p = 0; p < 2; ++p) {
            float keep = b3 ? acc[t][2 + p] : acc[t][p];
            float send = b3 ? acc[t][p] : acc[t][2 + p];
            s16[t][p] = keep + __shfl_xor(send, 8, 64);
        }
    float s8[4][2];
#pragma unroll
    for (int t = 0; t < 4; ++t)
#pragma unroll
        for (int p = 0; p < 2; ++p) {
            float keep = b0 ? s16[2 * t + 1][p] : s16[2 * t][p];
            float send = b0 ? s16[2 * t][p] : s16[2 * t + 1][p];
            s8[t][p] = keep + __shfl_xor(send, 1, 64);
        }
    float s4[2][2];
#pragma unroll
    for (int u = 0; u < 2; ++u)
#pragma unroll
        for (int p = 0; p < 2; ++p) {
            float keep = b1 ? s8[2 * u + 1][p] : s8[2 * u][p];
            float send = b1 ? s8[2 * u][p] : s8[2 * u + 1][p];
            s4[u][p] = keep + __shfl_xor(send, 2, 64);
        }
    float s2[2];
#pragma unroll
    for (int p = 0; p < 2; ++p) {
        float keep = b2 ? s4[1][p] : s4[0][p];
        float send = b2 ? s4[0][p] : s4[1][p];
        s2[p] = keep + __shfl_xor(send, 4, 64);
    }
    float2 st; st.x = s2[0]; st.y = s2[1];
    *(float2*)&S[(size_t)a * HH + (c & 7) * 16 + (q << 2) + (b3 << 1)] = st;
}

// ---------------------------------------------------------------------------
// GRU via MFMA + fused next-layer XW.
// Block = 16 atoms, 4 waves; wave w owns n-range w*32..w*32+31 of each gate.
// A = S tile (bf16, LDS, pad 132); B = WcT/W1xT bf16 [n][k] (global).
// C layout: atom = q*4+r, n = ntile*16 + c.
// ---------------------------------------------------------------------------
__global__ __launch_bounds__(256) void grux_mfma_kernel(
    const float* __restrict__ S, const unsigned short* __restrict__ WcT,
    const float* __restrict__ P, const float* __restrict__ bih,
    const float* __restrict__ bhh, const int* __restrict__ rowptr,
    float* __restrict__ X, int N,
    const unsigned short* __restrict__ W1xT, const float* __restrict__ b1next,
    float* __restrict__ XW, int do_xw)
{
    __shared__ __align__(16) unsigned short Sb[16][132];
    __shared__ __align__(16) unsigned short Xb[16][132];
    int tid = threadIdx.x;
    int abase = blockIdx.x * 16;

    // stage S tile -> bf16 LDS (thread t: atom t>>4, 8-float chunk t&15)
    {
        int a = tid >> 4, ch = tid & 15;
        int aa = abase + a; if (aa >= N) aa = N - 1;
        const float* src = S + (size_t)aa * HH + ch * 8;
        float4 v0 = *(const float4*)src;
        float4 v1 = *(const float4*)(src + 4);
        unsigned short* dst = &Sb[a][ch * 8];
        dst[0] = f2bf(v0.x); dst[1] = f2bf(v0.y);
        dst[2] = f2bf(v0.z); dst[3] = f2bf(v0.w);
        dst[4] = f2bf(v1.x); dst[5] = f2bf(v1.y);
        dst[6] = f2bf(v1.z); dst[7] = f2bf(v1.w);
    }
    __syncthreads();

    int w = tid >> 6, lane = tid & 63, c = lane & 15, q = lane >> 4;

    // 3 gates x 2 ntiles: n = g*128 + w*32 + t*16 + c
    floatx4 Cg[3][2];
#pragma unroll
    for (int g = 0; g < 3; ++g)
#pragma unroll
        for (int t = 0; t < 2; ++t) Cg[g][t] = floatx4{0.f, 0.f, 0.f, 0.f};

#pragma unroll
    for (int kt = 0; kt < 4; ++kt) {
        short8 A = *(const short8*)&Sb[c][kt * 32 + q * 8];
#pragma unroll
        for (int g = 0; g < 3; ++g)
#pragma unroll
            for (int t = 0; t < 2; ++t) {
                int nrow = g * 128 + w * 32 + t * 16 + c;
                short8 B = *(const short8*)&WcT[(size_t)nrow * HH + kt * 32 + q * 8];
                Cg[g][t] = __builtin_amdgcn_mfma_f32_16x16x32_bf16(A, B, Cg[g][t], 0, 0, 0);
            }
    }

    // GRU epilogue on C-fragments
#pragma unroll
    for (int r = 0; r < 4; ++r) {
        int am = q * 4 + r;
        int a = abase + am;
        bool ok = a < N;
        float deg = ok ? (float)(rowptr[a + 1] - rowptr[a]) : 0.f;
#pragma unroll
        for (int t = 0; t < 2; ++t) {
            int n = w * 32 + t * 16 + c;
            float g0 = Cg[0][t][r] + deg * P[n]       + bih[n];
            float g1 = Cg[1][t][r] + deg * P[128 + n] + bih[128 + n];
            float g2 = Cg[2][t][r] + deg * P[256 + n] + bih[256 + n];
            float rr = fast_sigmoid(g0 + bhh[n]);
            float zz = fast_sigmoid(g1 + bhh[128 + n]);
            float nn = fast_tanh(g2 + rr * bhh[256 + n]);
            float xv = 0.f;
            if (ok) {
                xv = X[(size_t)a * HH + n] + (1.f - zz) * nn;
                X[(size_t)a * HH + n] = xv;
            }
            Xb[am][n] = f2bf(xv);
        }
    }

    if (!do_xw) return;
    __syncthreads();

    floatx4 Cx[2];
    Cx[0] = floatx4{0.f, 0.f, 0.f, 0.f};
    Cx[1] = floatx4{0.f, 0.f, 0.f, 0.f};
#pragma unroll
    for (int kt = 0; kt < 4; ++kt) {
        short8 A = *(const short8*)&Xb[c][kt * 32 + q * 8];
#pragma unroll
        for (int t = 0; t < 2; ++t) {
            int nrow = w * 32 + t * 16 + c;
            short8 B = *(const short8*)&W1xT[(size_t)nrow * HH + kt * 32 + q * 8];
            Cx[t] = __builtin_amdgcn_mfma_f32_16x16x32_bf16(A, B, Cx[t], 0, 0, 0);
        }
    }
#pragma unroll
    for (int r = 0; r < 4; ++r) {
        int a = abase + q * 4 + r;
        if (a >= N) continue;
#pragma unroll
        for (int t = 0; t < 2; ++t) {
            int n = w * 32 + t * 16 + c;
            XW[(size_t)a * HH + n] = Cx[t][r] + b1next[n];
        }
    }
}

// LayerNorm -> d_out x region (no atomics)
__global__ __launch_bounds__(256) void ln_kernel(
    const float* __restrict__ X, const float* __restrict__ g,
    const float* __restrict__ b, float* __restrict__ out, int N)
{
    int a = blockIdx.x * 4 + (threadIdx.x >> 6);
    int lane = threadIdx.x & 63;
    if (a >= N) return;
    float v0 = X[(size_t)a * HH + lane];
    float v1 = X[(size_t)a * HH + 64 + lane];
    float sm = v0 + v1;
    for (int off = 32; off > 0; off >>= 1) sm += __shfl_xor(sm, off, 64);
    float mu = sm * (1.f / 128.f);
    float d0 = v0 - mu, d1 = v1 - mu;
    float vq = d0 * d0 + d1 * d1;
    for (int off = 32; off > 0; off >>= 1) vq += __shfl_xor(vq, off, 64);
    float inv = rsqrtf(vq * (1.f / 128.f) + 1e-5f);
    out[(size_t)a * HH + lane] = d0 * inv * g[lane] + b[lane];
    out[(size_t)a * HH + 64 + lane] = d1 * inv * g[64 + lane] + b[64 + lane];
}

// Block-per-molecule mean pool over sorted batch segments.
__global__ __launch_bounds__(256) void pool_kernel(
    const float* __restrict__ outx, const int* __restrict__ bptr,
    float* __restrict__ outg)
{
    __shared__ float sm[256];
    int m = blockIdx.x, t = threadIdx.x;
    int n = t & 127, s = t >> 7;
    int a0 = bptr[m], a1 = bptr[m + 1];
    float acc = 0.f;
    for (int a = a0 + s; a < a1; a += 2)
        acc += outx[(size_t)a * HH + n];
    sm[t] = acc;
    __syncthreads();
    if (t < 128) {
        float cnt = (float)(a1 - a0);
        outg[(size_t)m * HH + t] = (sm[t] + sm[t + 128]) / fmaxf(cnt, 1.f);
    }
}

extern "C" void kernel_launch(void* const* d_in, const int* in_sizes, int n_in,
                              void* d_out, int out_size, void* d_ws, size_t ws_size,
                              hipStream_t stream)
{
    const int*   an   = (const int*)d_in[0];
    const float* pos  = (const float*)d_in[1];
    const int*   bat  = (const int*)d_in[2];
    const int*   eidx = (const int*)d_in[3];
    const float* emb  = (const float*)d_in[4];
    const float* W1   = (const float*)d_in[5];
    const float* b1   = (const float*)d_in[6];
    const float* W2   = (const float*)d_in[7];
    const float* b2   = (const float*)d_in[8];
    const float* Wih  = (const float*)d_in[9];
    const float* bih  = (const float*)d_in[10];
    const float* bhh  = (const float*)d_in[11];
    const float* lng  = (const float*)d_in[12];
    const float* lnb  = (const float*)d_in[13];

    int N = in_sizes[0];
    int E = in_sizes[3] / 2;
    int M = out_size / HH - N;
    const int* erow = eidx;
    const int* ecol = eidx + E;

    float* ws   = (float*)d_ws;
    size_t off = 0;
    float* X    = ws + off; off += (size_t)N * HH;
    float* S    = ws + off; off += (size_t)N * HH;
    float* XW   = ws + off; off += (size_t)N * HH;
    float* P    = ws + off; off += LL * 384;
    float* dist = ws + off; off += E;
    int* rowptr = (int*)(ws + off); off += N + 1;
    int* bptr   = (int*)(ws + off); off += M + 1;
    off = (off + 3) & ~(size_t)3;
    unsigned short* W1rT = (unsigned short*)(ws + off); off += (size_t)LL * HH * 32;
    unsigned short* W1xT = (unsigned short*)(ws + off); off += (size_t)LL * HH * 64;
    unsigned short* WcT  = (unsigned short*)(ws + off); off += (size_t)LL * 384 * 64;

    float* outx = (float*)d_out;
    float* outg = outx + (size_t)N * HH;

    int PT = (E > N ? E : N);

    // one-time prep
    init_x_kernel<<<(N * HH + 255) / 256, 256, 0, stream>>>(an, emb, X, N * HH);
    ptr_kernel<<<(PT + 255) / 256, 256, 0, stream>>>(erow, rowptr, E, N, bat, bptr, M);
    dist_kernel<<<(E + 255) / 256, 256, 0, stream>>>(pos, erow, ecol, dist, E);
    w1rt_kernel<<<(LL * HH * 64 + 255) / 256, 256, 0, stream>>>(W1, W1rT);
    w1xt_kernel<<<(LL * HH * HH + 255) / 256, 256, 0, stream>>>(W1, W1xT);
    wc_kernel<<<LL * HH, 384, 0, stream>>>(W2, Wih, WcT);
    p_kernel<<<LL, 384, 0, stream>>>(b2, Wih, P);

    // layer 0 XW
    xw_kernel<<<(N + XAB - 1) / XAB, 256, 0, stream>>>(X, W1, b1, XW, N);

    int edge_blocks = (N + 3) / 4;
    int grux_blocks = (N + 15) / 16;
    for (int l = 0; l < LL; ++l) {
        edge_mfma_kernel<<<edge_blocks, 256, 0, stream>>>(
            XW, W1rT + (size_t)l * HH * 64, dist, rowptr, ecol, S, N);
        int do_xw = (l < LL - 1) ? 1 : 0;
        int ln = (l + 1 < LL) ? l + 1 : l;
        grux_mfma_kernel<<<grux_blocks, 256, 0, stream>>>(
            S, WcT + (size_t)l * 384 * HH, P + l * 384,
            bih + l * 384, bhh + l * 384, rowptr, X, N,
            W1xT + (size_t)ln * HH * HH, b1 + (size_t)ln * HH, XW, do_xw);
    }

    ln_kernel<<<(N + 3) / 4, 256, 0, stream>>>(X, lng, lnb, outx, N);
    pool_kernel<<<M, 256, 0, stream>>>(outx, bptr, outg);
}

// Round 6
// 387.627 us; speedup vs baseline: 2.0229x; 1.1901x over previous
//
#include <hip/hip_runtime.h>
#include <hip/hip_bf16.h>
#include <math.h>

// ---------------------------------------------------------------------------
// InfomaxEncoder, round 6:
//  - edge: persistent waves (grid-stride over atoms; A-frags loaded once),
//    v_perm bf16 packing, exp2-direct transcendentals, per-nt MFMA consume
//    with C initialized from the XW gather (round-4 structure).
//  - all one-time prep fused into ONE grid-partitioned kernel (19->12 launches)
//  - grux: P/bih/bhh/deg hoisted ahead of LDS staging barrier.
// Factorizations (exact): XW = X@W1_x + b1; S = segsum silu(XW[col] + rbf@W1r)
// over sorted rows; gi = S@Wc + deg*P + b_ih, Wc = W2@W_ih, P = b2@W_ih.
// ---------------------------------------------------------------------------

#define HH 128
#define RR 50
#define LL 4
#define L2E 1.4426950408889634f

typedef __attribute__((ext_vector_type(8))) short short8;
typedef __attribute__((ext_vector_type(4))) float floatx4;

__device__ __forceinline__ unsigned short f2bf(float f) {
    unsigned u = __float_as_uint(f);
    unsigned r = (u + 0x7fffu + ((u >> 16) & 1u)) >> 16;
    return (unsigned short)r;
}
// pack two floats to packed bf16 (lo|hi<<16), round-half-up via +0x8000 + v_perm
__device__ __forceinline__ unsigned pack_bf2(float lo, float hi) {
    unsigned u0 = __float_as_uint(lo) + 0x8000u;
    unsigned u1 = __float_as_uint(hi) + 0x8000u;
    return __builtin_amdgcn_perm(u1, u0, 0x07060302);
}
__device__ __forceinline__ float fast_sigmoid(float x) {
    return __builtin_amdgcn_rcpf(1.f + __builtin_amdgcn_exp2f(x * (-L2E)));
}
__device__ __forceinline__ float fast_tanh(float x) {
    x = fminf(fmaxf(x, -15.f), 15.f);
    float t = __builtin_amdgcn_exp2f(x * (2.f * L2E));
    return (t - 1.f) * __builtin_amdgcn_rcpf(t + 1.f);
}
__device__ __forceinline__ int imin(int a, int b) { return a < b ? a : b; }

// ---------------------------------------------------------------------------
// Fused one-time prep: initX | rowptr/bptr | dist | W1rT | W1xT | WcT | P
// ---------------------------------------------------------------------------
__global__ __launch_bounds__(256) void prep_kernel(
    const int* __restrict__ an, const float* __restrict__ emb,
    float* __restrict__ X,
    const float* __restrict__ pos, const int* __restrict__ erow,
    const int* __restrict__ ecol, float* __restrict__ dist,
    int* __restrict__ rowptr, int* __restrict__ bptr,
    const int* __restrict__ batch,
    const float* __restrict__ W1, unsigned short* __restrict__ W1rT,
    unsigned short* __restrict__ W1xT,
    const float* __restrict__ W2, const float* __restrict__ Wih,
    unsigned short* __restrict__ WcT,
    const float* __restrict__ b2, float* __restrict__ P,
    int N, int E, int M)
{
    int gidx = blockIdx.x * 256 + threadIdx.x;
    int c0 = N * HH;
    if (gidx < c0) {                       // initX
        int i = gidx >> 7, n = gidx & 127;
        int z = an[i];
        z = z < 0 ? 0 : (z > 99 ? 99 : z);
        X[gidx] = emb[z * HH + n];
        return;
    }
    gidx -= c0;
    int PT = E > N ? E : N;
    if (gidx < PT) {                       // rowptr + bptr
        int i = gidx;
        if (i < E) {
            int rc = erow[i];
            int rp = (i > 0) ? erow[i - 1] : -1;
            for (int r = rp + 1; r <= rc; ++r) rowptr[r] = i;
            if (i == E - 1)
                for (int r = rc + 1; r <= N; ++r) rowptr[r] = E;
        }
        if (i < N) {
            int bc = batch[i];
            int bp = (i > 0) ? batch[i - 1] : -1;
            for (int m = bp + 1; m <= bc; ++m) bptr[m] = i;
            if (i == N - 1)
                for (int m = bc + 1; m <= M; ++m) bptr[m] = N;
        }
        return;
    }
    gidx -= PT;
    if (gidx < E) {                        // dist
        int e = gidx;
        int r = erow[e], c = ecol[e];
        float dx = pos[r * 3 + 0] - pos[c * 3 + 0];
        float dy = pos[r * 3 + 1] - pos[c * 3 + 1];
        float dz = pos[r * 3 + 2] - pos[c * 3 + 2];
        dist[e] = sqrtf(dx * dx + dy * dy + dz * dz);
        return;
    }
    gidx -= E;
    if (gidx < LL * HH * 64) {             // W1rT[l][n][k]
        int l = gidx >> 13, rem = gidx & 8191, n = rem >> 6, k = rem & 63;
        float v = (k < RR) ? W1[((size_t)l * 178 + 128 + k) * HH + n] : 0.f;
        W1rT[gidx] = f2bf(v);
        return;
    }
    gidx -= LL * HH * 64;
    if (gidx < LL * HH * HH) {             // W1xT[l][n][k] = W1[l][k][n]
        int l = gidx >> 14, rem = gidx & 16383, n = rem >> 7, k = rem & 127;
        W1xT[gidx] = f2bf(W1[((size_t)l * 178 + k) * HH + n]);
        return;
    }
    gidx -= LL * HH * HH;
    if (gidx < LL * HH * 384) {            // WcT[l][j][i] = sum_k W2[l][i][k]Wih[l][k][j]
        int l = gidx / (HH * 384), rem = gidx % (HH * 384);
        int i = rem / 384, j = rem % 384;
        const float* w2row = W2 + ((size_t)l * HH + i) * HH;
        const float* wih = Wih + (size_t)l * HH * 384;
        float acc = 0.f;
#pragma unroll 4
        for (int k = 0; k < HH; ++k)
            acc = fmaf(w2row[k], wih[(size_t)k * 384 + j], acc);
        WcT[((size_t)l * 384 + j) * HH + i] = f2bf(acc);
        return;
    }
    gidx -= LL * HH * 384;
    if (gidx < LL * 384) {                 // P[l][j] = sum_k b2[l][k]Wih[l][k][j]
        int l = gidx / 384, j = gidx % 384;
        const float* b2l = b2 + (size_t)l * HH;
        const float* wih = Wih + (size_t)l * HH * 384;
        float acc = 0.f;
#pragma unroll 4
        for (int k = 0; k < HH; ++k)
            acc = fmaf(b2l[k], wih[(size_t)k * 384 + j], acc);
        P[gidx] = acc;
    }
}

// XW = X @ W1_x + b1 (layer 0 only; later layers fused into grux_mfma)
#define XAB 32
__global__ __launch_bounds__(256) void xw_kernel(
    const float* __restrict__ X, const float* __restrict__ W,
    const float* __restrict__ bias, float* __restrict__ XW, int N)
{
    __shared__ __align__(16) float A[XAB][HH];
    int tid = threadIdx.x;
    int abase = blockIdx.x * XAB;
    for (int idx = tid; idx < XAB * HH; idx += 256) {
        int a = idx >> 7, k = idx & 127;
        A[a][k] = (abase + a < N) ? X[(size_t)(abase + a) * HH + k] : 0.f;
    }
    __syncthreads();
    int n = tid & 127, s = tid >> 7;
    float acc[16];
#pragma unroll
    for (int i = 0; i < 16; ++i) acc[i] = 0.f;
    for (int kc = 0; kc < 32; ++kc) {
        float w0 = W[(4 * kc + 0) * HH + n];
        float w1 = W[(4 * kc + 1) * HH + n];
        float w2 = W[(4 * kc + 2) * HH + n];
        float w3 = W[(4 * kc + 3) * HH + n];
#pragma unroll
        for (int i = 0; i < 16; ++i) {
            float4 av = *(const float4*)&A[s * 16 + i][4 * kc];
            acc[i] = fmaf(av.x, w0, acc[i]);
            acc[i] = fmaf(av.y, w1, acc[i]);
            acc[i] = fmaf(av.z, w2, acc[i]);
            acc[i] = fmaf(av.w, w3, acc[i]);
        }
    }
    float b = bias[n];
#pragma unroll
    for (int i = 0; i < 16; ++i) {
        int a = abase + s * 16 + i;
        if (a < N) XW[(size_t)a * HH + n] = acc[i] + b;
    }
}

// ---------------------------------------------------------------------------
// Edge pass: persistent waves, grid-stride over atoms. Per 16-edge tile:
// rbf in-register (exp2 + v_perm pack), 2-tile-ahead index prefetch,
// C initialized from XW gather, per-nt consume.
// ---------------------------------------------------------------------------
__global__ __launch_bounds__(256) void edge_mfma_kernel(
    const float* __restrict__ XW, const unsigned short* __restrict__ W1rT,
    const float* __restrict__ dist, const int* __restrict__ rowptr,
    const int* __restrict__ ecol, float* __restrict__ S, int N, int nwaves)
{
    int wid = (blockIdx.x << 2) + (threadIdx.x >> 6);
    int lane = threadIdx.x & 63;
    int c = lane & 15, q = lane >> 4;

    // A-frags (layer weights) loaded ONCE per wave lifetime
    short8 Afr[8][2];
#pragma unroll
    for (int nt = 0; nt < 8; ++nt) {
        Afr[nt][0] = *(const short8*)&W1rT[(nt * 16 + c) * 64 + q * 8];
        Afr[nt][1] = *(const short8*)&W1rT[(nt * 16 + c) * 64 + 32 + q * 8];
    }

    const float stepc = 5.0f / 49.0f;
    const float negc = -50.f * L2E;        // exp(-50 t^2) = exp2(negc * t^2)
    float kqs = (float)(q << 3) * stepc;   // (q*8)*step

    for (int a = wid; a < N; a += nwaves) {
        int es = rowptr[a], ee = rowptr[a + 1];
        float acc[8][4];
#pragma unroll
        for (int nt = 0; nt < 8; ++nt)
#pragma unroll
            for (int r = 0; r < 4; ++r) acc[nt][r] = 0.f;

        if (es < ee) {
            int last = ee - 1;
            int ce0 = imin(es + c, last);
            float dcur = dist[ce0];
            int colcur = ecol[ce0];
            int ce1 = imin(es + 16 + c, last);
            float dnxt = dist[ce1];
            int colnxt = ecol[ce1];

            for (int eb = es; eb < ee; eb += 16) {
                const float* xwrow = XW + (size_t)colcur * HH;
                float4 gx[8];
#pragma unroll
                for (int nt = 0; nt < 8; ++nt)
                    gx[nt] = *(const float4*)&xwrow[nt * 16 + (q << 2)];

                float d_t = dcur;
                dcur = dnxt; colcur = colnxt;
                int ce2 = imin(eb + 32 + c, last);
                dnxt = dist[ce2];
                colnxt = ecol[ce2];

                // B-gen: k = half*32 + q*8 + j
                float dq0 = d_t - kqs;
                float dq1 = dq0 - 32.f * stepc;
                union { unsigned u[4]; short8 s; } ub0, ub1;
#pragma unroll
                for (int p = 0; p < 4; ++p) {
                    float t0 = dq0 - (float)(2 * p) * stepc;
                    float t1 = dq0 - (float)(2 * p + 1) * stepc;
                    float e0 = __builtin_amdgcn_exp2f(negc * t0 * t0);
                    float e1 = __builtin_amdgcn_exp2f(negc * t1 * t1);
                    ub0.u[p] = pack_bf2(e0, e1);
                    float t2 = dq1 - (float)(2 * p) * stepc;
                    float t3 = dq1 - (float)(2 * p + 1) * stepc;
                    float e2 = __builtin_amdgcn_exp2f(negc * t2 * t2);
                    float e3 = __builtin_amdgcn_exp2f(negc * t3 * t3);
                    ub1.u[p] = pack_bf2(e2, e3);
                }
                short8 B0 = ub0.s, B1 = ub1.s;
                float msk = ((eb + c) < ee) ? 1.f : 0.f;

#pragma unroll
                for (int nt = 0; nt < 8; ++nt) {
                    floatx4 C = {gx[nt].x, gx[nt].y, gx[nt].z, gx[nt].w};
                    C = __builtin_amdgcn_mfma_f32_16x16x32_bf16(Afr[nt][0], B0, C, 0, 0, 0);
                    C = __builtin_amdgcn_mfma_f32_16x16x32_bf16(Afr[nt][1], B1, C, 0, 0, 0);
#pragma unroll
                    for (int r = 0; r < 4; ++r) {
                        float h = C[r];
                        float v = h * fast_sigmoid(h);   // silu
                        acc[nt][r] = fmaf(v, msk, acc[nt][r]);
                    }
                }
            }
        }

        // Index-splitting butterfly over the 16 edge-classes (c bits).
        int b3 = (c >> 3) & 1, b0 = c & 1, b1 = (c >> 1) & 1, b2 = (c >> 2) & 1;
        float s16[8][2];
#pragma unroll
        for (int t = 0; t < 8; ++t)
#pragma unroll
            for (int p = 0; p < 2; ++p) {
                float keep = b3 ? acc[t][2 + p] : acc[t][p];
                float send = b3 ? acc[t][p] : acc[t][2 + p];
                s16[t][p] = keep + __shfl_xor(send, 8, 64);
            }
        float s8[4][2];
#pragma unroll
        for (int t = 0; t < 4; ++t)
#pragma unroll
            for (int p = 0; p < 2; ++p) {
                float keep = b0 ? s16[2 * t + 1][p] : s16[2 * t][p];
                float send = b0 ? s16[2 * t][p] : s16[2 * t + 1][p];
                s8[t][p] = keep + __shfl_xor(send, 1, 64);
            }
        float s4[2][2];
#pragma unroll
        for (int u = 0; u < 2; ++u)
#pragma unroll
            for (int p = 0; p < 2; ++p) {
                float keep = b1 ? s8[2 * u + 1][p] : s8[2 * u][p];
                float send = b1 ? s8[2 * u][p] : s8[2 * u + 1][p];
                s4[u][p] = keep + __shfl_xor(send, 2, 64);
            }
        float s2[2];
#pragma unroll
        for (int p = 0; p < 2; ++p) {
            float keep = b2 ? s4[1][p] : s4[0][p];
            float send = b2 ? s4[0][p] : s4[1][p];
            s2[p] = keep + __shfl_xor(send, 4, 64);
        }
        float2 st; st.x = s2[0]; st.y = s2[1];
        *(float2*)&S[(size_t)a * HH + (c & 7) * 16 + (q << 2) + (b3 << 1)] = st;
    }
}

// ---------------------------------------------------------------------------
// GRU via MFMA + fused next-layer XW. Block = 16 atoms, 4 waves; wave w owns
// n-range w*32.. of each gate. Bias/deg loads hoisted ahead of staging.
// ---------------------------------------------------------------------------
__global__ __launch_bounds__(256) void grux_mfma_kernel(
    const float* __restrict__ S, const unsigned short* __restrict__ WcT,
    const float* __restrict__ P, const float* __restrict__ bih,
    const float* __restrict__ bhh, const int* __restrict__ rowptr,
    float* __restrict__ X, int N,
    const unsigned short* __restrict__ W1xT, const float* __restrict__ b1next,
    float* __restrict__ XW, int do_xw)
{
    __shared__ __align__(16) unsigned short Sb[16][132];
    __shared__ __align__(16) unsigned short Xb[16][132];
    int tid = threadIdx.x;
    int abase = blockIdx.x * 16;
    int w = tid >> 6, lane = tid & 63, c = lane & 15, q = lane >> 4;

    // hoisted epilogue operands (independent of staging)
    float pn[2][3], bi[2][3], bh[2][3], deg[4];
#pragma unroll
    for (int t = 0; t < 2; ++t) {
        int n = w * 32 + t * 16 + c;
#pragma unroll
        for (int g = 0; g < 3; ++g) {
            pn[t][g] = P[g * 128 + n];
            bi[t][g] = bih[g * 128 + n];
            bh[t][g] = bhh[g * 128 + n];
        }
    }
#pragma unroll
    for (int r = 0; r < 4; ++r) {
        int a = abase + q * 4 + r;
        deg[r] = (a < N) ? (float)(rowptr[a + 1] - rowptr[a]) : 0.f;
    }

    // stage S tile -> bf16 LDS
    {
        int a = tid >> 4, ch = tid & 15;
        int aa = abase + a; if (aa >= N) aa = N - 1;
        const float* src = S + (size_t)aa * HH + ch * 8;
        float4 v0 = *(const float4*)src;
        float4 v1 = *(const float4*)(src + 4);
        unsigned* dst = (unsigned*)&Sb[a][ch * 8];
        dst[0] = pack_bf2(v0.x, v0.y);
        dst[1] = pack_bf2(v0.z, v0.w);
        dst[2] = pack_bf2(v1.x, v1.y);
        dst[3] = pack_bf2(v1.z, v1.w);
    }
    __syncthreads();

    floatx4 Cg[3][2];
#pragma unroll
    for (int g = 0; g < 3; ++g)
#pragma unroll
        for (int t = 0; t < 2; ++t) Cg[g][t] = floatx4{0.f, 0.f, 0.f, 0.f};

#pragma unroll
    for (int kt = 0; kt < 4; ++kt) {
        short8 A = *(const short8*)&Sb[c][kt * 32 + q * 8];
#pragma unroll
        for (int g = 0; g < 3; ++g)
#pragma unroll
            for (int t = 0; t < 2; ++t) {
                int nrow = g * 128 + w * 32 + t * 16 + c;
                short8 B = *(const short8*)&WcT[(size_t)nrow * HH + kt * 32 + q * 8];
                Cg[g][t] = __builtin_amdgcn_mfma_f32_16x16x32_bf16(A, B, Cg[g][t], 0, 0, 0);
            }
    }

#pragma unroll
    for (int r = 0; r < 4; ++r) {
        int am = q * 4 + r;
        int a = abase + am;
        bool ok = a < N;
#pragma unroll
        for (int t = 0; t < 2; ++t) {
            int n = w * 32 + t * 16 + c;
            float g0 = Cg[0][t][r] + deg[r] * pn[t][0] + bi[t][0];
            float g1 = Cg[1][t][r] + deg[r] * pn[t][1] + bi[t][1];
            float g2 = Cg[2][t][r] + deg[r] * pn[t][2] + bi[t][2];
            float rr = fast_sigmoid(g0 + bh[t][0]);
            float zz = fast_sigmoid(g1 + bh[t][1]);
            float nn = fast_tanh(g2 + rr * bh[t][2]);
            float xv = 0.f;
            if (ok) {
                xv = X[(size_t)a * HH + n] + (1.f - zz) * nn;
                X[(size_t)a * HH + n] = xv;
            }
            Xb[am][n] = f2bf(xv);
        }
    }

    if (!do_xw) return;
    __syncthreads();

    floatx4 Cx[2];
    Cx[0] = floatx4{0.f, 0.f, 0.f, 0.f};
    Cx[1] = floatx4{0.f, 0.f, 0.f, 0.f};
#pragma unroll
    for (int kt = 0; kt < 4; ++kt) {
        short8 A = *(const short8*)&Xb[c][kt * 32 + q * 8];
#pragma unroll
        for (int t = 0; t < 2; ++t) {
            int nrow = w * 32 + t * 16 + c;
            short8 B = *(const short8*)&W1xT[(size_t)nrow * HH + kt * 32 + q * 8];
            Cx[t] = __builtin_amdgcn_mfma_f32_16x16x32_bf16(A, B, Cx[t], 0, 0, 0);
        }
    }
#pragma unroll
    for (int r = 0; r < 4; ++r) {
        int a = abase + q * 4 + r;
        if (a >= N) continue;
#pragma unroll
        for (int t = 0; t < 2; ++t) {
            int n = w * 32 + t * 16 + c;
            XW[(size_t)a * HH + n] = Cx[t][r] + b1next[n];
        }
    }
}

// LayerNorm -> d_out x region (no atomics)
__global__ __launch_bounds__(256) void ln_kernel(
    const float* __restrict__ X, const float* __restrict__ g,
    const float* __restrict__ b, float* __restrict__ out, int N)
{
    int a = blockIdx.x * 4 + (threadIdx.x >> 6);
    int lane = threadIdx.x & 63;
    if (a >= N) return;
    float v0 = X[(size_t)a * HH + lane];
    float v1 = X[(size_t)a * HH + 64 + lane];
    float sm = v0 + v1;
    for (int off = 32; off > 0; off >>= 1) sm += __shfl_xor(sm, off, 64);
    float mu = sm * (1.f / 128.f);
    float d0 = v0 - mu, d1 = v1 - mu;
    float vq = d0 * d0 + d1 * d1;
    for (int off = 32; off > 0; off >>= 1) vq += __shfl_xor(vq, off, 64);
    float inv = rsqrtf(vq * (1.f / 128.f) + 1e-5f);
    out[(size_t)a * HH + lane] = d0 * inv * g[lane] + b[lane];
    out[(size_t)a * HH + 64 + lane] = d1 * inv * g[64 + lane] + b[64 + lane];
}

// Block-per-molecule mean pool over sorted batch segments.
__global__ __launch_bounds__(256) void pool_kernel(
    const float* __restrict__ outx, const int* __restrict__ bptr,
    float* __restrict__ outg)
{
    __shared__ float sm[256];
    int m = blockIdx.x, t = threadIdx.x;
    int n = t & 127, s = t >> 7;
    int a0 = bptr[m], a1 = bptr[m + 1];
    float acc = 0.f;
    for (int a = a0 + s; a < a1; a += 2)
        acc += outx[(size_t)a * HH + n];
    sm[t] = acc;
    __syncthreads();
    if (t < 128) {
        float cnt = (float)(a1 - a0);
        outg[(size_t)m * HH + t] = (sm[t] + sm[t + 128]) / fmaxf(cnt, 1.f);
    }
}

extern "C" void kernel_launch(void* const* d_in, const int* in_sizes, int n_in,
                              void* d_out, int out_size, void* d_ws, size_t ws_size,
                              hipStream_t stream)
{
    const int*   an   = (const int*)d_in[0];
    const float* pos  = (const float*)d_in[1];
    const int*   bat  = (const int*)d_in[2];
    const int*   eidx = (const int*)d_in[3];
    const float* emb  = (const float*)d_in[4];
    const float* W1   = (const float*)d_in[5];
    const float* b1   = (const float*)d_in[6];
    const float* W2   = (const float*)d_in[7];
    const float* b2   = (const float*)d_in[8];
    const float* Wih  = (const float*)d_in[9];
    const float* bih  = (const float*)d_in[10];
    const float* bhh  = (const float*)d_in[11];
    const float* lng  = (const float*)d_in[12];
    const float* lnb  = (const float*)d_in[13];

    int N = in_sizes[0];
    int E = in_sizes[3] / 2;
    int M = out_size / HH - N;
    const int* erow = eidx;
    const int* ecol = eidx + E;

    float* ws   = (float*)d_ws;
    size_t off = 0;
    float* X    = ws + off; off += (size_t)N * HH;
    float* S    = ws + off; off += (size_t)N * HH;
    float* XW   = ws + off; off += (size_t)N * HH;
    float* P    = ws + off; off += LL * 384;
    float* dist = ws + off; off += E;
    int* rowptr = (int*)(ws + off); off += N + 1;
    int* bptr   = (int*)(ws + off); off += M + 1;
    off = (off + 3) & ~(size_t)3;
    unsigned short* W1rT = (unsigned short*)(ws + off); off += (size_t)LL * HH * 32;
    unsigned short* W1xT = (unsigned short*)(ws + off); off += (size_t)LL * HH * 64;
    unsigned short* WcT  = (unsigned short*)(ws + off); off += (size_t)LL * 384 * 64;

    float* outx = (float*)d_out;
    float* outg = outx + (size_t)N * HH;

    int PT = (E > N ? E : N);
    long total = (long)N * HH + PT + E + LL * HH * 64 + LL * HH * HH
               + LL * HH * 384 + LL * 384;
    int prep_blocks = (int)((total + 255) / 256);

    prep_kernel<<<prep_blocks, 256, 0, stream>>>(
        an, emb, X, pos, erow, ecol, dist, rowptr, bptr, bat,
        W1, W1rT, W1xT, W2, Wih, WcT, b2, P, N, E, M);

    xw_kernel<<<(N + XAB - 1) / XAB, 256, 0, stream>>>(X, W1, b1, XW, N);

    int eblocks = (N + 3) / 4; if (eblocks > 1024) eblocks = 1024;
    int nwaves = eblocks * 4;
    int grux_blocks = (N + 15) / 16;
    for (int l = 0; l < LL; ++l) {
        edge_mfma_kernel<<<eblocks, 256, 0, stream>>>(
            XW, W1rT + (size_t)l * HH * 64, dist, rowptr, ecol, S, N, nwaves);
        int do_xw = (l < LL - 1) ? 1 : 0;
        int ln = (l + 1 < LL) ? l + 1 : l;
        grux_mfma_kernel<<<grux_blocks, 256, 0, stream>>>(
            S, WcT + (size_t)l * 384 * HH, P + l * 384,
            bih + l * 384, bhh + l * 384, rowptr, X, N,
            W1xT + (size_t)ln * HH * HH, b1 + (size_t)ln * HH, XW, do_xw);
    }

    ln_kernel<<<(N + 3) / 4, 256, 0, stream>>>(X, lng, lnb, outx, N);
    pool_kernel<<<M, 256, 0, stream>>>(outx, bptr, outg);
}